// Round 3
// baseline (3142.027 us; speedup 1.0000x reference)
//
#include <hip/hip_runtime.h>
#include <hip/hip_bf16.h>
#include <stdint.h>

#define BB 16
#define CC 256
#define NN 2048
#define KK 10
#define WW 128

typedef unsigned short ushort_t;

// converted-weight table offsets (fp32 elements)
#define TW1_O 0
#define TB1_O 32768
#define TW2_O 32896
#define TB2_O 34432
#define TW3_O 34560
#define TB3_O 67328
#define SW1_O 67584
#define SB1_O 133120
#define SW2_O 133248
#define SB2_O 133760
#define SW3_O 133888
#define SB3_O 166656

__device__ __forceinline__ float bflo(unsigned p){ union{unsigned u; float f;} v; v.u = p << 16; return v.f; }
__device__ __forceinline__ float bfhi(unsigned p){ union{unsigned u; float f;} v; v.u = p & 0xffff0000u; return v.f; }
__device__ __forceinline__ float bfs(ushort_t u){ union{unsigned u; float f;} v; v.u = ((unsigned)u) << 16; return v.f; }
__device__ __forceinline__ ushort_t f2bf16(float f){
  __hip_bfloat16 h = __float2bfloat16(f);
  return *reinterpret_cast<ushort_t*>(&h);
}
__device__ __forceinline__ uint2 f4_to_bf4(float4 v){
  uint2 r;
  r.x = (unsigned)f2bf16(v.x) | ((unsigned)f2bf16(v.y) << 16);
  r.y = (unsigned)f2bf16(v.z) | ((unsigned)f2bf16(v.w) << 16);
  return r;
}

// ---------------- D0: detect input dtype. fp32 read as bf16 pairs -> garbage exponents ----------------
__global__ void k_detect(const void* __restrict__ xraw, int* __restrict__ flag){
  __shared__ float red[256];
  int t = threadIdx.x;
  const ushort_t* p = (const ushort_t*)xraw;
  float m = 0.f;
  for(int i = t; i < 1024; i += 256){
    float v = bfs(p[i]);
    v = fabsf(v);
    if(!(v < 1e30f)) v = 1e30f;   // clamp inf/nan
    m = fmaxf(m, v);
  }
  red[t] = m; __syncthreads();
  for(int s = 128; s > 0; s >>= 1){ if(t < s) red[t] = fmaxf(red[t], red[t+s]); __syncthreads(); }
  if(t == 0) flag[0] = (red[0] > 1e3f) ? 1 : 0;   // 1 => inputs are fp32
}

// ---------------- D1: convert all weights/biases to fp32 table ----------------
__global__ void k_convw(const void* p0, const void* p1, const void* p2, const void* p3,
                        const void* p4, const void* p5, const void* p6, const void* p7,
                        const void* p8, const void* p9, const void* p10, const void* p11,
                        float* __restrict__ dst, const int* __restrict__ flag){
  const int counts[12] = {32768,128,1536,128,32768,256,65536,128,512,128,32768,256};
  const int offs[12]   = {TW1_O,TB1_O,TW2_O,TB2_O,TW3_O,TB3_O,SW1_O,SB1_O,SW2_O,SB2_O,SW3_O,SB3_O};
  int a = blockIdx.y;
  const void* src;
  switch(a){
    case 0: src=p0; break; case 1: src=p1; break; case 2: src=p2; break;
    case 3: src=p3; break; case 4: src=p4; break; case 5: src=p5; break;
    case 6: src=p6; break; case 7: src=p7; break; case 8: src=p8; break;
    case 9: src=p9; break; case 10: src=p10; break; default: src=p11; break;
  }
  int cnt = counts[a], off = offs[a];
  int isf = flag[0];
  for(int i = blockIdx.x*256 + threadIdx.x; i < cnt; i += gridDim.x*256){
    float v = isf ? ((const float*)src)[i] : bfs(((const ushort_t*)src)[i]);
    dst[off + i] = v;
  }
}

// ---------------- D2: canonicalize x: xc (B,C,N) fp32 + xT (B,N,C) fp32 ----------------
__global__ void k_convx(const void* __restrict__ xraw, const int* __restrict__ flag,
                        float* __restrict__ xc, float* __restrict__ xT){
  __shared__ float tile[32][33];
  int isf = flag[0];
  int b = blockIdx.z;
  int n0 = blockIdx.x * 32;
  int c0 = blockIdx.y * 32;
  int tx = threadIdx.x, ty = threadIdx.y;
  #pragma unroll
  for(int r = 0; r < 4; r++){
    int c = c0 + ty + r*8;
    size_t off = ((size_t)b*CC + c)*NN + n0 + tx;
    float v = isf ? ((const float*)xraw)[off] : bfs(((const ushort_t*)xraw)[off]);
    xc[off] = v;
    tile[ty + r*8][tx] = v;
  }
  __syncthreads();
  #pragma unroll
  for(int r = 0; r < 4; r++){
    int n = n0 + ty + r*8;
    xT[((size_t)b*NN + n)*CC + c0 + tx] = tile[tx][ty + r*8];
  }
}

// ---------------- K1: row norms in double ----------------
__global__ void k_norms(const float* __restrict__ xT, double* __restrict__ xx){
  int row = blockIdx.x*4 + (threadIdx.x >> 6);
  int lane = threadIdx.x & 63;
  float4 q = *(const float4*)(xT + (size_t)row*CC + lane*4);
  double s = (double)q.x*q.x + (double)q.y*q.y + (double)q.z*q.z + (double)q.w*q.w;
  #pragma unroll
  for(int off = 32; off > 0; off >>= 1) s += __shfl_down(s, off);
  if(lane == 0) xx[row] = s;
}

// ---------------- K2: kNN (fp64-accurate Gram + per-row top-10) ----------------
__global__ __launch_bounds__(256) void k_knn(const float* __restrict__ xT,
                                             const double* __restrict__ xx,
                                             int* __restrict__ idxout){
  __shared__ float  xi[32][68];
  __shared__ float  xj[64][68];
  __shared__ double tval[32][66];
  __shared__ double xxj[64];
  __shared__ double lv[32][10];
  __shared__ int    li[32][10];

  int b  = blockIdx.x;
  int i0 = blockIdx.y * 32;
  int t  = threadIdx.x;
  if(t < 32){
    #pragma unroll
    for(int s = 0; s < 10; s++){ lv[t][s] = -1e300; li[t][s] = -1; }
  }
  const int ti = t & 7;
  const int tj = t >> 3;
  double worstv = -1e300;
  const size_t xbase = (size_t)b * NN;
  __syncthreads();

  for(int jt = 0; jt < 32; jt++){
    int j0 = jt * 64;
    if(t < 64) xxj[t] = xx[xbase + j0 + t];
    double acc[4][2];
    #pragma unroll
    for(int a = 0; a < 4; a++){ acc[a][0] = 0.0; acc[a][1] = 0.0; }

    for(int cc = 0; cc < 4; cc++){
      int c0 = cc*64;
      __syncthreads();
      {
        int r = t >> 3, c8 = (t & 7) * 8;
        const float* src = xT + (xbase + i0 + r)*CC + c0 + c8;
        float4 qa = *(const float4*)src;
        float4 qb = *(const float4*)(src + 4);
        xi[r][c8+0]=qa.x; xi[r][c8+1]=qa.y; xi[r][c8+2]=qa.z; xi[r][c8+3]=qa.w;
        xi[r][c8+4]=qb.x; xi[r][c8+5]=qb.y; xi[r][c8+6]=qb.z; xi[r][c8+7]=qb.w;
      }
      {
        int r = t >> 3, c8 = (t & 7) * 8;
        #pragma unroll
        for(int h = 0; h < 2; h++){
          int rr = r + 32*h;
          const float* src = xT + (xbase + j0 + rr)*CC + c0 + c8;
          float4 qa = *(const float4*)src;
          float4 qb = *(const float4*)(src + 4);
          xj[rr][c8+0]=qa.x; xj[rr][c8+1]=qa.y; xj[rr][c8+2]=qa.z; xj[rr][c8+3]=qa.w;
          xj[rr][c8+4]=qb.x; xj[rr][c8+5]=qb.y; xj[rr][c8+6]=qb.z; xj[rr][c8+7]=qb.w;
        }
      }
      __syncthreads();
      #pragma unroll 4
      for(int c = 0; c < 64; c += 4){
        float4 xiv[4], xjv[2];
        #pragma unroll
        for(int a = 0; a < 4; a++) xiv[a] = *(const float4*)&xi[ti + 8*a][c];
        #pragma unroll
        for(int h = 0; h < 2; h++) xjv[h] = *(const float4*)&xj[tj + 32*h][c];
        #pragma unroll
        for(int a = 0; a < 4; a++){
          #pragma unroll
          for(int h = 0; h < 2; h++){
            acc[a][h] += (double)xiv[a].x * xjv[h].x;
            acc[a][h] += (double)xiv[a].y * xjv[h].y;
            acc[a][h] += (double)xiv[a].z * xjv[h].z;
            acc[a][h] += (double)xiv[a].w * xjv[h].w;
          }
        }
      }
    }
    #pragma unroll
    for(int a = 0; a < 4; a++){
      #pragma unroll
      for(int h = 0; h < 2; h++){
        int il = ti + 8*a, jl = tj + 32*h;
        tval[il][jl] = 2.0*acc[a][h] - xxj[jl];
      }
    }
    __syncthreads();
    if(t < 32){
      int i = t;
      #pragma unroll 1
      for(int jl = 0; jl < 64; jl++){
        double v = tval[i][jl];
        if(v > worstv){
          int ws = 0; double bv = lv[i][0]; int bi = li[i][0];
          #pragma unroll
          for(int s = 1; s < 10; s++){
            double sv = lv[i][s]; int si = li[i][s];
            if(sv < bv || (sv == bv && si > bi)){ ws = s; bv = sv; bi = si; }
          }
          lv[i][ws] = v; li[i][ws] = j0 + jl;
          double m = lv[i][0];
          #pragma unroll
          for(int s = 1; s < 10; s++) m = fmin(m, lv[i][s]);
          worstv = m;
        }
      }
    }
    __syncthreads();
  }
  for(int e = t; e < 320; e += 256){
    int i = e / 10, k = e % 10;
    idxout[((size_t)b*NN + i0 + i)*KK + k] = li[i][k];
  }
}

// ---------------- K3: pointwise convs: y1, y2(+sb1), t1=relu(tw1@x+tb1) ----------------
__global__ __launch_bounds__(128) void k_pointwise(
    const float* __restrict__ xT, const float* __restrict__ Wc,
    float* __restrict__ y1t, float* __restrict__ y2t, float* __restrict__ t1t){
  int b  = blockIdx.y;
  int n0 = blockIdx.x * 4;
  int o  = threadIdx.x;
  const float* w1 = Wc + SW1_O + o*512;
  const float* w2 = w1 + 256;
  const float* w3 = Wc + TW1_O + o*256;
  const float* xr = xT + ((size_t)b*NN + n0)*CC;
  float a1[4] = {0,0,0,0}, a2[4] = {0,0,0,0}, a3[4] = {0,0,0,0};
  for(int c = 0; c < 256; c += 4){
    float4 f1 = *(const float4*)(w1 + c);
    float4 f2 = *(const float4*)(w2 + c);
    float4 f3 = *(const float4*)(w3 + c);
    #pragma unroll
    for(int j = 0; j < 4; j++){
      float4 fx = *(const float4*)(xr + (size_t)j*CC + c);
      a1[j] += f1.x*fx.x + f1.y*fx.y + f1.z*fx.z + f1.w*fx.w;
      a2[j] += f2.x*fx.x + f2.y*fx.y + f2.z*fx.z + f2.w*fx.w;
      a3[j] += f3.x*fx.x + f3.y*fx.y + f3.z*fx.z + f3.w*fx.w;
    }
  }
  float b1 = Wc[SB1_O + o];
  float bt = Wc[TB1_O + o];
  #pragma unroll
  for(int j = 0; j < 4; j++){
    size_t r = ((size_t)b*NN + n0 + j)*WW + o;
    y1t[r] = a1[j];
    y2t[r] = a2[j] + b1;
    t1t[r] = fmaxf(a3[j] + bt, 0.f);
  }
}

// ---------------- K4: graph tail: v -> u -> sw3 GEMM -> max over k ----------------
__global__ __launch_bounds__(256) void k_s3max(
    const float* __restrict__ y1t, const float* __restrict__ y2t,
    const int* __restrict__ idx, const float* __restrict__ Wc,
    float* __restrict__ soutT){
  __shared__ ushort_t w3[128][132];
  __shared__ float U[40][132];
  __shared__ float y2s[4][128];
  __shared__ float pmax[8][128];
  __shared__ int idxs[40];
  int b  = blockIdx.z;
  int n0 = blockIdx.y * 4;
  int ch = blockIdx.x;
  int t  = threadIdx.x;
  #pragma unroll
  for(int e = 0; e < 16; e++){
    int qq = t + 256*e;            // quad id over 128x128/4
    int cl = qq >> 5;
    int c4 = (qq & 31) * 4;
    float4 v = *(const float4*)(Wc + SW3_O + ((size_t)(ch*128 + cl))*WW + c4);
    *(uint2*)&w3[cl][c4] = f4_to_bf4(v);
  }
  if(t < 40) idxs[t] = idx[((size_t)b*NN + n0 + t/10)*KK + (t%10)];
  #pragma unroll
  for(int e = 0; e < 2; e++){
    int lid = t + 256*e;
    int r = lid >> 7, o = lid & 127;
    y2s[r][o] = y2t[((size_t)b*NN + n0 + r)*WW + o];
  }
  __syncthreads();
  {
    int o = t & 127;
    int half = t >> 7;
    float4 wv = *(const float4*)(Wc + SW2_O + o*4);
    float b2 = Wc[SB2_O + o];
    int ob = o & ~3;
    for(int pp = 0; pp < 20; pp++){
      int p = pp*2 + half;
      int nl = p / 10;
      int j = idxs[p];
      const float4 yv  = *(const float4*)(y1t + ((size_t)b*NN + j)*WW + ob);
      const float4 y2v = *(const float4*)&y2s[nl][ob];
      float acc = b2;
      acc += wv.x*fmaxf(yv.x + y2v.x, 0.f);
      acc += wv.y*fmaxf(yv.y + y2v.y, 0.f);
      acc += wv.z*fmaxf(yv.z + y2v.z, 0.f);
      acc += wv.w*fmaxf(yv.w + y2v.w, 0.f);
      U[p][o] = fmaxf(acc, 0.f);
    }
  }
  __syncthreads();
  {
    int tc = t & 31;
    int tr = t >> 5;
    float acc[5][4];
    #pragma unroll
    for(int r = 0; r < 5; r++){ acc[r][0]=0.f; acc[r][1]=0.f; acc[r][2]=0.f; acc[r][3]=0.f; }
    for(int w = 0; w < 128; w += 4){
      float4 uv[5];
      #pragma unroll
      for(int r = 0; r < 5; r++) uv[r] = *(const float4*)&U[tr*5+r][w];
      float wf[4][4];
      #pragma unroll
      for(int g = 0; g < 4; g++){
        uint2 q = *(const uint2*)&w3[tc+32*g][w];
        wf[g][0]=bflo(q.x); wf[g][1]=bfhi(q.x); wf[g][2]=bflo(q.y); wf[g][3]=bfhi(q.y);
      }
      #pragma unroll
      for(int r = 0; r < 5; r++){
        #pragma unroll
        for(int g = 0; g < 4; g++)
          acc[r][g] += uv[r].x*wf[g][0] + uv[r].y*wf[g][1] + uv[r].z*wf[g][2] + uv[r].w*wf[g][3];
      }
    }
    #pragma unroll
    for(int g = 0; g < 4; g++){
      float m = acc[0][g];
      #pragma unroll
      for(int r = 1; r < 5; r++) m = fmaxf(m, acc[r][g]);
      pmax[tr][tc+32*g] = m;
    }
  }
  __syncthreads();
  #pragma unroll
  for(int e = 0; e < 2; e++){
    int lid = t + 256*e;
    int g = lid >> 7;
    int col = lid & 127;
    float v = fmaxf(pmax[2*g][col], pmax[2*g+1][col]) + Wc[SB3_O + ch*128 + col];
    soutT[((size_t)b*NN + n0+g)*CC + ch*128 + col] = v;
  }
}

// ---------------- K5: temporal tail: grouped conv3 -> tw3 GEMM ----------------
__global__ __launch_bounds__(256) void k_tout(
    const float* __restrict__ t1t, const float* __restrict__ Wc,
    float* __restrict__ toutT){
  __shared__ float t2s[64][132];
  __shared__ ushort_t w3s[64][132];
  int b  = blockIdx.z;
  int n0 = blockIdx.y * 64;
  int cb = blockIdx.x * 64;
  int t  = threadIdx.x;
  {
    int o = t & 127;
    int rbase = t >> 7;
    float w2v[12];
    #pragma unroll
    for(int z = 0; z < 12; z++) w2v[z] = Wc[TW2_O + o*12 + z];
    float bv = Wc[TB2_O + o];
    int ob = o & ~3;
    for(int e = 0; e < 32; e++){
      int r = rbase + 2*e;
      int n = n0 + r;
      float acc = bv;
      #pragma unroll
      for(int d = 0; d < 3; d++){
        int nn2 = n + d - 1;
        if(nn2 >= 0 && nn2 < NN){
          float4 tv = *(const float4*)(t1t + ((size_t)b*NN + nn2)*WW + ob);
          acc += w2v[0*3+d]*tv.x + w2v[1*3+d]*tv.y + w2v[2*3+d]*tv.z + w2v[3*3+d]*tv.w;
        }
      }
      t2s[r][o] = fmaxf(acc, 0.f);
    }
  }
  #pragma unroll
  for(int e = 0; e < 8; e++){
    int qq = t + 256*e;            // quads over 64x128/4
    int cl = qq >> 5;
    int c4 = (qq & 31) * 4;
    float4 v = *(const float4*)(Wc + TW3_O + ((size_t)(cb + cl))*WW + c4);
    *(uint2*)&w3s[cl][c4] = f4_to_bf4(v);
  }
  __syncthreads();
  int tr = t >> 4, tc = t & 15;
  float acc[4][4];
  #pragma unroll
  for(int r = 0; r < 4; r++){ acc[r][0]=0.f; acc[r][1]=0.f; acc[r][2]=0.f; acc[r][3]=0.f; }
  for(int w = 0; w < 128; w += 4){
    float4 uv[4];
    #pragma unroll
    for(int r = 0; r < 4; r++) uv[r] = *(const float4*)&t2s[tr+16*r][w];
    float wf[4][4];
    #pragma unroll
    for(int g = 0; g < 4; g++){
      uint2 q = *(const uint2*)&w3s[tc+16*g][w];
      wf[g][0]=bflo(q.x); wf[g][1]=bfhi(q.x); wf[g][2]=bflo(q.y); wf[g][3]=bfhi(q.y);
    }
    #pragma unroll
    for(int r = 0; r < 4; r++){
      #pragma unroll
      for(int g = 0; g < 4; g++)
        acc[r][g] += uv[r].x*wf[g][0] + uv[r].y*wf[g][1] + uv[r].z*wf[g][2] + uv[r].w*wf[g][3];
    }
  }
  #pragma unroll
  for(int g = 0; g < 4; g++){
    float bv = Wc[TB3_O + cb + tc + 16*g];
    #pragma unroll
    for(int r = 0; r < 4; r++)
      toutT[((size_t)b*NN + n0 + tr + 16*r)*CC + cb + tc + 16*g] = acc[r][g] + bv;
  }
}

// ---------------- K6: out = relu(toutT + soutT (transposed) + xc), dtype per flag ----------------
__global__ void k_final(const float* __restrict__ toutT, const float* __restrict__ soutT,
                        const float* __restrict__ xc, const int* __restrict__ flag,
                        void* __restrict__ outraw){
  __shared__ float tile[32][33];
  int isf = flag[0];
  int b = blockIdx.z;
  int n0 = blockIdx.x*32, c0 = blockIdx.y*32;
  int tx = threadIdx.x, ty = threadIdx.y;
  #pragma unroll
  for(int r = 0; r < 4; r++){
    int n = n0 + ty + 8*r;
    size_t off = ((size_t)b*NN + n)*CC + c0 + tx;
    tile[ty+8*r][tx] = toutT[off] + soutT[off];
  }
  __syncthreads();
  #pragma unroll
  for(int r = 0; r < 4; r++){
    int c = c0 + ty + 8*r;
    size_t off = ((size_t)b*CC + c)*NN + n0 + tx;
    float v = fmaxf(tile[tx][ty+8*r] + xc[off], 0.f);
    if(isf) ((float*)outraw)[off] = v;
    else    ((ushort_t*)outraw)[off] = f2bf16(v);
  }
}

extern "C" void kernel_launch(void* const* d_in, const int* in_sizes, int n_in,
                              void* d_out, int out_size, void* d_ws, size_t ws_size,
                              hipStream_t stream){
  char* ws = (char*)d_ws;
  // workspace layout (bytes), all offsets 256-aligned
  int*    flag  = (int*)   (ws + 0);
  float*  Wc    = (float*) (ws + 256);          //   667,648 B
  float*  xT    = (float*) (ws + 1048576);      // 33,554,432
  float*  xc    = (float*) (ws + 34603008);     // 33,554,432
  double* xx    = (double*)(ws + 68157440);     //    262,144
  int*    idx   = (int*)   (ws + 68419584);     //  1,310,720
  float*  y1t   = (float*) (ws + 69730304);     // 16,777,216
  float*  y2t   = (float*) (ws + 86507520);     // 16,777,216
  float*  t1t   = (float*) (ws + 103284736);    // 16,777,216
  float*  soutT = (float*) (ws + 120061952);    // 33,554,432
  float*  toutT = (float*) (ws + 153616384);    // 33,554,432  (end 187,170,816)

  k_detect<<<1, 256, 0, stream>>>(d_in[0], flag);
  k_convw<<<dim3(64,12), 256, 0, stream>>>(d_in[1], d_in[2], d_in[3], d_in[4], d_in[5], d_in[6],
                                           d_in[7], d_in[8], d_in[9], d_in[10], d_in[11], d_in[12],
                                           Wc, flag);
  k_convx<<<dim3(64,8,16), dim3(32,8), 0, stream>>>(d_in[0], flag, xc, xT);
  k_norms<<<dim3(8192), dim3(256), 0, stream>>>(xT, xx);
  k_knn<<<dim3(16,64), dim3(256), 0, stream>>>(xT, xx, idx);
  k_pointwise<<<dim3(512,16), dim3(128), 0, stream>>>(xT, Wc, y1t, y2t, t1t);
  k_s3max<<<dim3(2,512,16), dim3(256), 0, stream>>>(y1t, y2t, idx, Wc, soutT);
  k_tout<<<dim3(4,32,16), dim3(256), 0, stream>>>(t1t, Wc, toutT);
  k_final<<<dim3(64,8,16), dim3(32,8), 0, stream>>>(toutT, soutT, xc, flag, d_out);
}

// Round 4
// 1602.304 us; speedup vs baseline: 1.9609x; 1.9609x over previous
//
#include <hip/hip_runtime.h>
#include <hip/hip_bf16.h>
#include <stdint.h>

#define BB 16
#define CC 256
#define NN 2048
#define KK 10
#define WW 128
#define DELTA 0.05f

typedef unsigned short ushort_t;
typedef __attribute__((ext_vector_type(8))) short short8;
typedef __attribute__((ext_vector_type(4))) float f32x4;

// converted-weight table offsets (fp32 elements)
#define TW1_O 0
#define TB1_O 32768
#define TW2_O 32896
#define TB2_O 34432
#define TW3_O 34560
#define TB3_O 67328
#define SW1_O 67584
#define SB1_O 133120
#define SW2_O 133248
#define SB2_O 133760
#define SW3_O 133888
#define SB3_O 166656

__device__ __forceinline__ float bflo(unsigned p){ union{unsigned u; float f;} v; v.u = p << 16; return v.f; }
__device__ __forceinline__ float bfhi(unsigned p){ union{unsigned u; float f;} v; v.u = p & 0xffff0000u; return v.f; }
__device__ __forceinline__ float bfs(ushort_t u){ union{unsigned u; float f;} v; v.u = ((unsigned)u) << 16; return v.f; }
__device__ __forceinline__ ushort_t f2bf16(float f){
  __hip_bfloat16 h = __float2bfloat16(f);
  return *reinterpret_cast<ushort_t*>(&h);
}
__device__ __forceinline__ uint2 f4_to_bf4(float4 v){
  uint2 r;
  r.x = (unsigned)f2bf16(v.x) | ((unsigned)f2bf16(v.y) << 16);
  r.y = (unsigned)f2bf16(v.z) | ((unsigned)f2bf16(v.w) << 16);
  return r;
}

// ---------------- D0: detect input dtype ----------------
__global__ void k_detect(const void* __restrict__ xraw, int* __restrict__ flag){
  __shared__ float red[256];
  int t = threadIdx.x;
  const ushort_t* p = (const ushort_t*)xraw;
  float m = 0.f;
  for(int i = t; i < 1024; i += 256){
    float v = bfs(p[i]);
    v = fabsf(v);
    if(!(v < 1e30f)) v = 1e30f;
    m = fmaxf(m, v);
  }
  red[t] = m; __syncthreads();
  for(int s = 128; s > 0; s >>= 1){ if(t < s) red[t] = fmaxf(red[t], red[t+s]); __syncthreads(); }
  if(t == 0) flag[0] = (red[0] > 1e3f) ? 1 : 0;   // 1 => inputs are fp32
}

// ---------------- D1: convert all weights/biases to fp32 table ----------------
__global__ void k_convw(const void* p0, const void* p1, const void* p2, const void* p3,
                        const void* p4, const void* p5, const void* p6, const void* p7,
                        const void* p8, const void* p9, const void* p10, const void* p11,
                        float* __restrict__ dst, const int* __restrict__ flag){
  const int counts[12] = {32768,128,1536,128,32768,256,65536,128,512,128,32768,256};
  const int offs[12]   = {TW1_O,TB1_O,TW2_O,TB2_O,TW3_O,TB3_O,SW1_O,SB1_O,SW2_O,SB2_O,SW3_O,SB3_O};
  int a = blockIdx.y;
  const void* src;
  switch(a){
    case 0: src=p0; break; case 1: src=p1; break; case 2: src=p2; break;
    case 3: src=p3; break; case 4: src=p4; break; case 5: src=p5; break;
    case 6: src=p6; break; case 7: src=p7; break; case 8: src=p8; break;
    case 9: src=p9; break; case 10: src=p10; break; default: src=p11; break;
  }
  int cnt = counts[a], off = offs[a];
  int isf = flag[0];
  for(int i = blockIdx.x*256 + threadIdx.x; i < cnt; i += gridDim.x*256){
    float v = isf ? ((const float*)src)[i] : bfs(((const ushort_t*)src)[i]);
    dst[off + i] = v;
  }
}

// ---------------- D2: canonicalize x -> xT fp32 (B,N,C) + bf16 hi/lo ----------------
__global__ void k_convx(const void* __restrict__ xraw, const int* __restrict__ flag,
                        float* __restrict__ xT, ushort_t* __restrict__ xThi,
                        ushort_t* __restrict__ xTlo){
  __shared__ float tile[32][33];
  int isf = flag[0];
  int b = blockIdx.z;
  int n0 = blockIdx.x * 32;
  int c0 = blockIdx.y * 32;
  int tx = threadIdx.x, ty = threadIdx.y;
  #pragma unroll
  for(int r = 0; r < 4; r++){
    int c = c0 + ty + r*8;
    size_t off = ((size_t)b*CC + c)*NN + n0 + tx;
    float v = isf ? ((const float*)xraw)[off] : bfs(((const ushort_t*)xraw)[off]);
    tile[ty + r*8][tx] = v;
  }
  __syncthreads();
  #pragma unroll
  for(int r = 0; r < 4; r++){
    int n = n0 + ty + r*8;
    size_t off = ((size_t)b*NN + n)*CC + c0 + tx;
    float v = tile[tx][ty + r*8];
    xT[off] = v;
    ushort_t hi = f2bf16(v);
    xThi[off] = hi;
    xTlo[off] = f2bf16(v - bfs(hi));
  }
}

// ---------------- K1: row norms (fp64 + fp32 copy) ----------------
__global__ void k_norms(const float* __restrict__ xT, double* __restrict__ xx,
                        float* __restrict__ xxf){
  int row = blockIdx.x*4 + (threadIdx.x >> 6);
  int lane = threadIdx.x & 63;
  float4 q = *(const float4*)(xT + (size_t)row*CC + lane*4);
  double s = (double)q.x*q.x + (double)q.y*q.y + (double)q.z*q.z + (double)q.w*q.w;
  #pragma unroll
  for(int off = 32; off > 0; off >>= 1) s += __shfl_down(s, off);
  if(lane == 0){ xx[row] = s; xxf[row] = (float)s; }
}

// ---------------- K2: kNN — bf16 hi/lo MFMA screen + exact fp64 recheck ----------------
// grid (B, N/32); block 256 (4 waves). i-tile 32 rows; j-chunks of 128.
__global__ __launch_bounds__(256, 2) void k_knn(
    const ushort_t* __restrict__ xThi, const ushort_t* __restrict__ xTlo,
    const float* __restrict__ xT, const double* __restrict__ xx,
    const float* __restrict__ xxf, int* __restrict__ idxout){
  __shared__ char xjraw[36864];            // xjhi[128][72] + xjlo[128][72] bf16; reused as merge bufs
  ushort_t* xjhi = (ushort_t*)xjraw;
  ushort_t* xjlo = (ushort_t*)(xjraw + 18432);
  float*    mval = (float*)xjraw;          // [32][96]
  int*      midx = (int*)(xjraw + 12288);  // [32][96]
  __shared__ float  keybuf[32][132];
  __shared__ float  xxs[128];
  __shared__ float  taus[32];
  __shared__ int    ambs[32];
  __shared__ double dval[32][24];
  __shared__ int    didx[32][24];
  __shared__ int    cnt[32];

  const int t    = threadIdx.x;
  const int lane = t & 63;
  const int w    = t >> 6;
  const int b    = blockIdx.x;
  const int i0   = blockIdx.y * 32;
  const size_t xb = (size_t)b * NN;
  const int l15  = lane & 15;
  const int q    = lane >> 4;

  // preload A fragments (Xi rows i0..i0+31), hi & lo, all K=256
  short8 ahi[2][8], alo[2][8];
  #pragma unroll
  for(int m = 0; m < 2; m++){
    const ushort_t* ph = xThi + (xb + i0 + 16*m + l15)*CC + q*8;
    const ushort_t* pl = xTlo + (xb + i0 + 16*m + l15)*CC + q*8;
    #pragma unroll
    for(int ks = 0; ks < 8; ks++){
      ahi[m][ks] = *(const short8*)(ph + ks*32);
      alo[m][ks] = *(const short8*)(pl + ks*32);
    }
  }

  float lv[12]; int li[12];
  #pragma unroll
  for(int k2 = 0; k2 < 12; k2++){ lv[k2] = -3e38f; li[k2] = -1; }

  const int srow = t >> 3;   // selection row 0..31
  const int ssub = t & 7;

  for(int jc = 0; jc < 16; jc++){
    const int j0 = jc * 128;
    f32x4 acc[2][2];
    #pragma unroll
    for(int m = 0; m < 2; m++)
      #pragma unroll
      for(int n2 = 0; n2 < 2; n2++)
        acc[m][n2] = (f32x4){0.f, 0.f, 0.f, 0.f};

    #pragma unroll
    for(int cc = 0; cc < 4; cc++){
      __syncthreads();
      if(cc == 0 && t < 128) xxs[t] = xxf[xb + j0 + t];
      { // stage xj chunk: 128 rows x 64 c, hi+lo
        int row = t >> 1, half = t & 1;
        const ushort_t* gh = xThi + (xb + j0 + row)*CC + cc*64 + half*32;
        const ushort_t* gl = xTlo + (xb + j0 + row)*CC + cc*64 + half*32;
        ushort_t* dh = xjhi + row*72 + half*32;
        ushort_t* dl = xjlo + row*72 + half*32;
        #pragma unroll
        for(int u = 0; u < 4; u++){
          *(uint4*)(dh + u*8) = *(const uint4*)(gh + u*8);
          *(uint4*)(dl + u*8) = *(const uint4*)(gl + u*8);
        }
      }
      __syncthreads();
      #pragma unroll
      for(int k2 = 0; k2 < 2; k2++){
        const int ks = cc*2 + k2;
        const int coff = k2*32 + q*8;
        short8 bhi[2], blo[2];
        #pragma unroll
        for(int n2 = 0; n2 < 2; n2++){
          int jr = 32*w + 16*n2 + l15;
          bhi[n2] = *(const short8*)(xjhi + jr*72 + coff);
          blo[n2] = *(const short8*)(xjlo + jr*72 + coff);
        }
        #pragma unroll
        for(int m = 0; m < 2; m++){
          #pragma unroll
          for(int n2 = 0; n2 < 2; n2++){
            acc[m][n2] = __builtin_amdgcn_mfma_f32_16x16x32_bf16(ahi[m][ks], bhi[n2], acc[m][n2], 0, 0, 0);
            acc[m][n2] = __builtin_amdgcn_mfma_f32_16x16x32_bf16(ahi[m][ks], blo[n2], acc[m][n2], 0, 0, 0);
            acc[m][n2] = __builtin_amdgcn_mfma_f32_16x16x32_bf16(alo[m][ks], bhi[n2], acc[m][n2], 0, 0, 0);
          }
        }
      }
    }
    __syncthreads();
    // keys: key = 2*dot - ||xj||^2 ; C/D layout: col=lane&15, row=(lane>>4)*4+reg
    #pragma unroll
    for(int m = 0; m < 2; m++){
      int rbase = 16*m + q*4;
      #pragma unroll
      for(int n2 = 0; n2 < 2; n2++){
        int col = 32*w + 16*n2 + l15;
        float xv = xxs[col];
        #pragma unroll
        for(int r = 0; r < 4; r++)
          keybuf[rbase + r][col] = 2.0f*acc[m][n2][r] - xv;
      }
    }
    __syncthreads();
    // selection scan: each thread 16 keys of its row, private top-12
    {
      const float* kp = &keybuf[srow][ssub*16];
      #pragma unroll
      for(int e4 = 0; e4 < 4; e4++){
        float4 kv = *(const float4*)(kp + e4*4);
        float ks4[4] = {kv.x, kv.y, kv.z, kv.w};
        #pragma unroll
        for(int e = 0; e < 4; e++){
          float key = ks4[e];
          if(key > lv[11]){
            float cv = key; int ci = j0 + ssub*16 + e4*4 + e;
            #pragma unroll
            for(int k2 = 0; k2 < 12; k2++){
              if(cv > lv[k2]){ float tv = lv[k2]; int ti = li[k2]; lv[k2] = cv; li[k2] = ci; cv = tv; ci = ti; }
            }
          }
        }
      }
    }
  }

  __syncthreads();
  // merge: dump per-thread top-12
  #pragma unroll
  for(int k2 = 0; k2 < 12; k2++){
    mval[srow*96 + ssub*12 + k2] = lv[k2];
    midx[srow*96 + ssub*12 + k2] = li[k2];
  }
  if(t < 32) cnt[t] = 0;
  __syncthreads();
  // row leaders: fp32 top-11 of merged 96 + ambiguity check
  float l11[11]; int i11[11];
  if(t < 32){
    #pragma unroll
    for(int k2 = 0; k2 < 11; k2++){ l11[k2] = -3e38f; i11[k2] = -1; }
    for(int e = 0; e < 96; e++){
      float v = mval[t*96 + e];
      if(v > l11[10]){
        float cv = v; int ci = midx[t*96 + e];
        #pragma unroll
        for(int k2 = 0; k2 < 11; k2++){
          if(cv > l11[k2]){ float tv = l11[k2]; int ti = i11[k2]; l11[k2] = cv; i11[k2] = ci; cv = tv; ci = ti; }
        }
      }
    }
    ambs[t] = (l11[9] - l11[10]) <= (2.0f*DELTA) ? 1 : 0;
    taus[t] = l11[9] - 2.0f*DELTA;
  }
  __syncthreads();
  // exact fp64 recheck of window candidates for ambiguous rows (rare)
  if(ambs[srow]){
    float tau = taus[srow];
    const float* xip = xT + (xb + i0 + srow)*CC;
    for(int k2 = 0; k2 < 12; k2++){
      if(lv[k2] >= tau && li[k2] >= 0){
        int jg = li[k2];
        const float* xjp = xT + (xb + jg)*CC;
        double s = 0.0;
        for(int c = 0; c < CC; c += 4){
          float4 a4 = *(const float4*)(xip + c);
          float4 b4 = *(const float4*)(xjp + c);
          s += (double)a4.x*b4.x + (double)a4.y*b4.y + (double)a4.z*b4.z + (double)a4.w*b4.w;
        }
        double key64 = 2.0*s - xx[xb + jg];
        int pos = atomicAdd(&cnt[srow], 1);
        if(pos < 24){ dval[srow][pos] = key64; didx[srow][pos] = jg; }
      }
    }
  }
  __syncthreads();
  if(t < 32){
    size_t obase = ((size_t)b*NN + i0 + t)*KK;
    if(!ambs[t]){
      #pragma unroll
      for(int k2 = 0; k2 < 10; k2++) idxout[obase + k2] = i11[k2];
    } else {
      int n = cnt[t]; if(n > 24) n = 24;
      double bl[10]; int bi[10];
      #pragma unroll
      for(int k2 = 0; k2 < 10; k2++){ bl[k2] = -1e300; bi[k2] = 0x7fffffff; }
      for(int e = 0; e < n; e++){
        double v = dval[t][e]; int j2 = didx[t][e];
        if(v > bl[9] || (v == bl[9] && j2 < bi[9])){
          double cv = v; int ci = j2;
          #pragma unroll
          for(int k2 = 0; k2 < 10; k2++){
            if(cv > bl[k2] || (cv == bl[k2] && ci < bi[k2])){
              double tv = bl[k2]; int ti = bi[k2]; bl[k2] = cv; bi[k2] = ci; cv = tv; ci = ti;
            }
          }
        }
      }
      #pragma unroll
      for(int k2 = 0; k2 < 10; k2++) idxout[obase + k2] = bi[k2];
    }
  }
}

// ---------------- K3: pointwise convs: y1, y2(+sb1), t1=relu(tw1@x+tb1) ----------------
__global__ __launch_bounds__(128) void k_pointwise(
    const float* __restrict__ xT, const float* __restrict__ Wc,
    float* __restrict__ y1t, float* __restrict__ y2t, float* __restrict__ t1t){
  int b  = blockIdx.y;
  int n0 = blockIdx.x * 4;
  int o  = threadIdx.x;
  const float* w1 = Wc + SW1_O + o*512;
  const float* w2 = w1 + 256;
  const float* w3 = Wc + TW1_O + o*256;
  const float* xr = xT + ((size_t)b*NN + n0)*CC;
  float a1[4] = {0,0,0,0}, a2[4] = {0,0,0,0}, a3[4] = {0,0,0,0};
  for(int c = 0; c < 256; c += 4){
    float4 f1 = *(const float4*)(w1 + c);
    float4 f2 = *(const float4*)(w2 + c);
    float4 f3 = *(const float4*)(w3 + c);
    #pragma unroll
    for(int j = 0; j < 4; j++){
      float4 fx = *(const float4*)(xr + (size_t)j*CC + c);
      a1[j] += f1.x*fx.x + f1.y*fx.y + f1.z*fx.z + f1.w*fx.w;
      a2[j] += f2.x*fx.x + f2.y*fx.y + f2.z*fx.z + f2.w*fx.w;
      a3[j] += f3.x*fx.x + f3.y*fx.y + f3.z*fx.z + f3.w*fx.w;
    }
  }
  float b1 = Wc[SB1_O + o];
  float bt = Wc[TB1_O + o];
  #pragma unroll
  for(int j = 0; j < 4; j++){
    size_t r = ((size_t)b*NN + n0 + j)*WW + o;
    y1t[r] = a1[j];
    y2t[r] = a2[j] + b1;
    t1t[r] = fmaxf(a3[j] + bt, 0.f);
  }
}

// ---------------- K4: graph tail: gather -> sw2 -> sw3 GEMM -> max over k ----------------
__global__ __launch_bounds__(256) void k_s3max(
    const float* __restrict__ y1t, const float* __restrict__ y2t,
    const int* __restrict__ idx, const float* __restrict__ Wc,
    float* __restrict__ soutT){
  __shared__ ushort_t w3[128][132];
  __shared__ float U[40][132];
  __shared__ float y2s[4][128];
  __shared__ float pmax[8][128];
  __shared__ int idxs[40];
  int b  = blockIdx.z;
  int n0 = blockIdx.y * 4;
  int ch = blockIdx.x;
  int t  = threadIdx.x;
  #pragma unroll
  for(int e = 0; e < 16; e++){
    int qq = t + 256*e;
    int cl = qq >> 5;
    int c4 = (qq & 31) * 4;
    float4 v = *(const float4*)(Wc + SW3_O + ((size_t)(ch*128 + cl))*WW + c4);
    *(uint2*)&w3[cl][c4] = f4_to_bf4(v);
  }
  if(t < 40) idxs[t] = idx[((size_t)b*NN + n0 + t/10)*KK + (t%10)];
  #pragma unroll
  for(int e = 0; e < 2; e++){
    int lid = t + 256*e;
    int r = lid >> 7, o = lid & 127;
    y2s[r][o] = y2t[((size_t)b*NN + n0 + r)*WW + o];
  }
  __syncthreads();
  {
    int o = t & 127;
    int half = t >> 7;
    float4 wv = *(const float4*)(Wc + SW2_O + o*4);
    float b2 = Wc[SB2_O + o];
    int ob = o & ~3;
    for(int pp = 0; pp < 20; pp++){
      int p = pp*2 + half;
      int nl = p / 10;
      int j = idxs[p];
      const float4 yv  = *(const float4*)(y1t + ((size_t)b*NN + j)*WW + ob);
      const float4 y2v = *(const float4*)&y2s[nl][ob];
      float acc = b2;
      acc += wv.x*fmaxf(yv.x + y2v.x, 0.f);
      acc += wv.y*fmaxf(yv.y + y2v.y, 0.f);
      acc += wv.z*fmaxf(yv.z + y2v.z, 0.f);
      acc += wv.w*fmaxf(yv.w + y2v.w, 0.f);
      U[p][o] = fmaxf(acc, 0.f);
    }
  }
  __syncthreads();
  {
    int tc = t & 31;
    int tr = t >> 5;
    float acc[5][4];
    #pragma unroll
    for(int r = 0; r < 5; r++){ acc[r][0]=0.f; acc[r][1]=0.f; acc[r][2]=0.f; acc[r][3]=0.f; }
    for(int w = 0; w < 128; w += 4){
      float4 uv[5];
      #pragma unroll
      for(int r = 0; r < 5; r++) uv[r] = *(const float4*)&U[tr*5+r][w];
      float wf[4][4];
      #pragma unroll
      for(int g = 0; g < 4; g++){
        uint2 q = *(const uint2*)&w3[tc+32*g][w];
        wf[g][0]=bflo(q.x); wf[g][1]=bfhi(q.x); wf[g][2]=bflo(q.y); wf[g][3]=bfhi(q.y);
      }
      #pragma unroll
      for(int r = 0; r < 5; r++){
        #pragma unroll
        for(int g = 0; g < 4; g++)
          acc[r][g] += uv[r].x*wf[g][0] + uv[r].y*wf[g][1] + uv[r].z*wf[g][2] + uv[r].w*wf[g][3];
      }
    }
    #pragma unroll
    for(int g = 0; g < 4; g++){
      float m = acc[0][g];
      #pragma unroll
      for(int r = 1; r < 5; r++) m = fmaxf(m, acc[r][g]);
      pmax[tr][tc+32*g] = m;
    }
  }
  __syncthreads();
  #pragma unroll
  for(int e = 0; e < 2; e++){
    int lid = t + 256*e;
    int g = lid >> 7;
    int col = lid & 127;
    float v = fmaxf(pmax[2*g][col], pmax[2*g+1][col]) + Wc[SB3_O + ch*128 + col];
    soutT[((size_t)b*NN + n0+g)*CC + ch*128 + col] = v;
  }
}

// ---------------- K5: temporal tail: grouped conv3 -> tw3 GEMM; ACCUMULATES into soutT ----------------
__global__ __launch_bounds__(256) void k_tout(
    const float* __restrict__ t1t, const float* __restrict__ Wc,
    float* __restrict__ soutT){
  __shared__ float t2s[64][132];
  __shared__ ushort_t w3s[64][132];
  int b  = blockIdx.z;
  int n0 = blockIdx.y * 64;
  int cb = blockIdx.x * 64;
  int t  = threadIdx.x;
  {
    int o = t & 127;
    int rbase = t >> 7;
    float w2v[12];
    #pragma unroll
    for(int z = 0; z < 12; z++) w2v[z] = Wc[TW2_O + o*12 + z];
    float bv = Wc[TB2_O + o];
    int ob = o & ~3;
    for(int e = 0; e < 32; e++){
      int r = rbase + 2*e;
      int n = n0 + r;
      float acc = bv;
      #pragma unroll
      for(int d = 0; d < 3; d++){
        int nn2 = n + d - 1;
        if(nn2 >= 0 && nn2 < NN){
          float4 tv = *(const float4*)(t1t + ((size_t)b*NN + nn2)*WW + ob);
          acc += w2v[0*3+d]*tv.x + w2v[1*3+d]*tv.y + w2v[2*3+d]*tv.z + w2v[3*3+d]*tv.w;
        }
      }
      t2s[r][o] = fmaxf(acc, 0.f);
    }
  }
  #pragma unroll
  for(int e = 0; e < 8; e++){
    int qq = t + 256*e;
    int cl = qq >> 5;
    int c4 = (qq & 31) * 4;
    float4 v = *(const float4*)(Wc + TW3_O + ((size_t)(cb + cl))*WW + c4);
    *(uint2*)&w3s[cl][c4] = f4_to_bf4(v);
  }
  __syncthreads();
  int tr = t >> 4, tc = t & 15;
  float acc[4][4];
  #pragma unroll
  for(int r = 0; r < 4; r++){ acc[r][0]=0.f; acc[r][1]=0.f; acc[r][2]=0.f; acc[r][3]=0.f; }
  for(int w = 0; w < 128; w += 4){
    float4 uv[4];
    #pragma unroll
    for(int r = 0; r < 4; r++) uv[r] = *(const float4*)&t2s[tr+16*r][w];
    float wf[4][4];
    #pragma unroll
    for(int g = 0; g < 4; g++){
      uint2 q = *(const uint2*)&w3s[tc+16*g][w];
      wf[g][0]=bflo(q.x); wf[g][1]=bfhi(q.x); wf[g][2]=bflo(q.y); wf[g][3]=bfhi(q.y);
    }
    #pragma unroll
    for(int r = 0; r < 4; r++){
      #pragma unroll
      for(int g = 0; g < 4; g++)
        acc[r][g] += uv[r].x*wf[g][0] + uv[r].y*wf[g][1] + uv[r].z*wf[g][2] + uv[r].w*wf[g][3];
    }
  }
  #pragma unroll
  for(int g = 0; g < 4; g++){
    float bv = Wc[TB3_O + cb + tc + 16*g];
    #pragma unroll
    for(int r = 0; r < 4; r++){
      size_t off = ((size_t)b*NN + n0 + tr + 16*r)*CC + cb + tc + 16*g;
      soutT[off] = soutT[off] + acc[r][g] + bv;   // sout + tout combined
    }
  }
}

// ---------------- K6: out = relu(comb (transposed) + x), dtype per flag ----------------
__global__ void k_final(const float* __restrict__ soutT, const void* __restrict__ xraw,
                        const int* __restrict__ flag, void* __restrict__ outraw){
  __shared__ float tile[32][33];
  int isf = flag[0];
  int b = blockIdx.z;
  int n0 = blockIdx.x*32, c0 = blockIdx.y*32;
  int tx = threadIdx.x, ty = threadIdx.y;
  #pragma unroll
  for(int r = 0; r < 4; r++){
    int n = n0 + ty + 8*r;
    size_t off = ((size_t)b*NN + n)*CC + c0 + tx;
    tile[ty+8*r][tx] = soutT[off];
  }
  __syncthreads();
  #pragma unroll
  for(int r = 0; r < 4; r++){
    int c = c0 + ty + 8*r;
    size_t off = ((size_t)b*CC + c)*NN + n0 + tx;
    float xv = isf ? ((const float*)xraw)[off] : bfs(((const ushort_t*)xraw)[off]);
    float v = fmaxf(tile[tx][ty+8*r] + xv, 0.f);
    if(isf) ((float*)outraw)[off] = v;
    else    ((ushort_t*)outraw)[off] = f2bf16(v);
  }
}

extern "C" void kernel_launch(void* const* d_in, const int* in_sizes, int n_in,
                              void* d_out, int out_size, void* d_ws, size_t ws_size,
                              hipStream_t stream){
  char* ws = (char*)d_ws;
  // workspace layout (bytes)
  int*      flag  = (int*)     (ws + 0);
  float*    Wc    = (float*)   (ws + 256);          //    667,648
  float*    xT    = (float*)   (ws + 1048576);      // 33,554,432
  double*   xx    = (double*)  (ws + 34603008);     //    262,144
  float*    xxf   = (float*)   (ws + 34865152);     //    131,072
  int*      idx   = (int*)     (ws + 34996224);     //  1,310,720
  float*    y1t   = (float*)   (ws + 36306944);     // 16,777,216
  float*    y2t   = (float*)   (ws + 53084160);     // 16,777,216
  float*    t1t   = (float*)   (ws + 69861376);     // 16,777,216
  float*    soutT = (float*)   (ws + 86638592);     // 33,554,432
  ushort_t* xThi  = (ushort_t*)(ws + 120193024);    // 16,777,216
  ushort_t* xTlo  = (ushort_t*)(ws + 136970240);    // 16,777,216  (end 153,747,456)

  k_detect<<<1, 256, 0, stream>>>(d_in[0], flag);
  k_convw<<<dim3(64,12), 256, 0, stream>>>(d_in[1], d_in[2], d_in[3], d_in[4], d_in[5], d_in[6],
                                           d_in[7], d_in[8], d_in[9], d_in[10], d_in[11], d_in[12],
                                           Wc, flag);
  k_convx<<<dim3(64,8,16), dim3(32,8), 0, stream>>>(d_in[0], flag, xT, xThi, xTlo);
  k_norms<<<dim3(8192), dim3(256), 0, stream>>>(xT, xx, xxf);
  k_knn<<<dim3(16,64), dim3(256), 0, stream>>>(xThi, xTlo, xT, xx, xxf, idx);
  k_pointwise<<<dim3(512,16), dim3(128), 0, stream>>>(xT, Wc, y1t, y2t, t1t);
  k_s3max<<<dim3(2,512,16), dim3(256), 0, stream>>>(y1t, y2t, idx, Wc, soutT);
  k_tout<<<dim3(4,32,16), dim3(256), 0, stream>>>(t1t, Wc, soutT);
  k_final<<<dim3(64,8,16), dim3(32,8), 0, stream>>>(soutT, d_in[0], flag, d_out);
}

// Round 5
// 1596.973 us; speedup vs baseline: 1.9675x; 1.0033x over previous
//
#include <hip/hip_runtime.h>
#include <hip/hip_bf16.h>
#include <stdint.h>

#define BB 16
#define CC 256
#define NN 2048
#define KK 10
#define WW 128
#define DELTA 0.05f

typedef unsigned short ushort_t;
typedef __attribute__((ext_vector_type(8))) _Float16 half8;
typedef __attribute__((ext_vector_type(4))) float f32x4;

// converted-weight table offsets (fp32 elements)
#define TW1_O 0
#define TB1_O 32768
#define TW2_O 32896
#define TB2_O 34432
#define TW3_O 34560
#define TB3_O 67328
#define SW1_O 67584
#define SB1_O 133120
#define SW2_O 133248
#define SB2_O 133760
#define SW3_O 133888
#define SB3_O 166656

__device__ __forceinline__ float bflo(unsigned p){ union{unsigned u; float f;} v; v.u = p << 16; return v.f; }
__device__ __forceinline__ float bfhi(unsigned p){ union{unsigned u; float f;} v; v.u = p & 0xffff0000u; return v.f; }
__device__ __forceinline__ float bfs(ushort_t u){ union{unsigned u; float f;} v; v.u = ((unsigned)u) << 16; return v.f; }
__device__ __forceinline__ ushort_t f2bf16(float f){
  __hip_bfloat16 h = __float2bfloat16(f);
  return *reinterpret_cast<ushort_t*>(&h);
}
__device__ __forceinline__ uint2 f4_to_bf4(float4 v){
  uint2 r;
  r.x = (unsigned)f2bf16(v.x) | ((unsigned)f2bf16(v.y) << 16);
  r.y = (unsigned)f2bf16(v.z) | ((unsigned)f2bf16(v.w) << 16);
  return r;
}

// ---------------- D0: detect input dtype ----------------
__global__ void k_detect(const void* __restrict__ xraw, int* __restrict__ flag){
  __shared__ float red[256];
  int t = threadIdx.x;
  const ushort_t* p = (const ushort_t*)xraw;
  float m = 0.f;
  for(int i = t; i < 1024; i += 256){
    float v = bfs(p[i]);
    v = fabsf(v);
    if(!(v < 1e30f)) v = 1e30f;
    m = fmaxf(m, v);
  }
  red[t] = m; __syncthreads();
  for(int s = 128; s > 0; s >>= 1){ if(t < s) red[t] = fmaxf(red[t], red[t+s]); __syncthreads(); }
  if(t == 0) flag[0] = (red[0] > 1e3f) ? 1 : 0;   // 1 => inputs are fp32
}

// ---------------- D1: convert all weights/biases to fp32 table ----------------
__global__ void k_convw(const void* p0, const void* p1, const void* p2, const void* p3,
                        const void* p4, const void* p5, const void* p6, const void* p7,
                        const void* p8, const void* p9, const void* p10, const void* p11,
                        float* __restrict__ dst, const int* __restrict__ flag){
  const int counts[12] = {32768,128,1536,128,32768,256,65536,128,512,128,32768,256};
  const int offs[12]   = {TW1_O,TB1_O,TW2_O,TB2_O,TW3_O,TB3_O,SW1_O,SB1_O,SW2_O,SB2_O,SW3_O,SB3_O};
  int a = blockIdx.y;
  const void* src;
  switch(a){
    case 0: src=p0; break; case 1: src=p1; break; case 2: src=p2; break;
    case 3: src=p3; break; case 4: src=p4; break; case 5: src=p5; break;
    case 6: src=p6; break; case 7: src=p7; break; case 8: src=p8; break;
    case 9: src=p9; break; case 10: src=p10; break; default: src=p11; break;
  }
  int cnt = counts[a], off = offs[a];
  int isf = flag[0];
  for(int i = blockIdx.x*256 + threadIdx.x; i < cnt; i += gridDim.x*256){
    float v = isf ? ((const float*)src)[i] : bfs(((const ushort_t*)src)[i]);
    dst[off + i] = v;
  }
}

// ---------------- D2: canonicalize x -> xT fp32 (B,N,C) + fp16 copy ----------------
__global__ void k_convx(const void* __restrict__ xraw, const int* __restrict__ flag,
                        float* __restrict__ xT, ushort_t* __restrict__ xTh){
  __shared__ float tile[32][33];
  int isf = flag[0];
  int b = blockIdx.z;
  int n0 = blockIdx.x * 32;
  int c0 = blockIdx.y * 32;
  int tx = threadIdx.x, ty = threadIdx.y;
  #pragma unroll
  for(int r = 0; r < 4; r++){
    int c = c0 + ty + r*8;
    size_t off = ((size_t)b*CC + c)*NN + n0 + tx;
    float v = isf ? ((const float*)xraw)[off] : bfs(((const ushort_t*)xraw)[off]);
    tile[ty + r*8][tx] = v;
  }
  __syncthreads();
  #pragma unroll
  for(int r = 0; r < 4; r++){
    int n = n0 + ty + r*8;
    size_t off = ((size_t)b*NN + n)*CC + c0 + tx;
    float v = tile[tx][ty + r*8];
    xT[off] = v;
    _Float16 h = (_Float16)v;
    xTh[off] = *reinterpret_cast<ushort_t*>(&h);
  }
}

// ---------------- K1: row norms (fp64 + fp32 copy) ----------------
__global__ void k_norms(const float* __restrict__ xT, double* __restrict__ xx,
                        float* __restrict__ xxf){
  int row = blockIdx.x*4 + (threadIdx.x >> 6);
  int lane = threadIdx.x & 63;
  float4 q = *(const float4*)(xT + (size_t)row*CC + lane*4);
  double s = (double)q.x*q.x + (double)q.y*q.y + (double)q.z*q.z + (double)q.w*q.w;
  #pragma unroll
  for(int off = 32; off > 0; off >>= 1) s += __shfl_down(s, off);
  if(lane == 0){ xx[row] = s; xxf[row] = (float)s; }
}

// ---------------- K2: kNN — fp16 single-pass MFMA screen + exact fp64 recheck ----------------
// grid (B, N/32); block 256 (4 waves). i-tile 32 rows; j-chunks of 128, staged 128c at a time.
__global__ __launch_bounds__(256, 3) void k_knn(
    const ushort_t* __restrict__ xTh, const float* __restrict__ xT,
    const double* __restrict__ xx, const float* __restrict__ xxf,
    int* __restrict__ idxout){
  __shared__ char xjraw[34816];            // xjh[128][136] fp16; later: merge + recheck bufs
  ushort_t* xjh = (ushort_t*)xjraw;
  float*    mval = (float*)xjraw;           // [32][96]   (12288 B)
  int*      midx = (int*)(xjraw + 12288);   // [32][96]   (12288 B)
  double*   dval = (double*)(xjraw + 24576);// [32][24]   (6144 B)
  int*      didx = (int*)(xjraw + 30720);   // [32][24]   (3072 B) -> 33792 <= 34816
  __shared__ float  keybuf[32][132];
  __shared__ float  xxs[128];
  __shared__ float  taus[32];
  __shared__ int    ambs[32];
  __shared__ int    cnt[32];

  const int t    = threadIdx.x;
  const int lane = t & 63;
  const int w    = t >> 6;
  const int b    = blockIdx.x;
  const int i0   = blockIdx.y * 32;
  const size_t xb = (size_t)b * NN;
  const int l15  = lane & 15;
  const int q    = lane >> 4;

  // preload A fragments (Xi rows i0..i0+31), fp16, all K=256: 64 VGPRs
  half8 afrag[2][8];
  #pragma unroll
  for(int m = 0; m < 2; m++){
    const ushort_t* pa = xTh + (xb + i0 + 16*m + l15)*CC + q*8;
    #pragma unroll
    for(int ks = 0; ks < 8; ks++)
      afrag[m][ks] = *(const half8*)(pa + ks*32);
  }

  float lv[12]; int li[12];
  #pragma unroll
  for(int k2 = 0; k2 < 12; k2++){ lv[k2] = -3e38f; li[k2] = -1; }

  const int srow = t >> 3;   // selection row 0..31
  const int ssub = t & 7;
  const int grow = t >> 1;   // staging row 0..127
  const int ghalf = t & 1;

  for(int jc = 0; jc < 16; jc++){
    const int j0 = jc * 128;
    f32x4 acc[2][2];
    #pragma unroll
    for(int m = 0; m < 2; m++)
      #pragma unroll
      for(int n2 = 0; n2 < 2; n2++)
        acc[m][n2] = (f32x4){0.f, 0.f, 0.f, 0.f};

    #pragma unroll
    for(int cc = 0; cc < 2; cc++){
      __syncthreads();
      if(cc == 0 && t < 128) xxs[t] = xxf[xb + j0 + t];
      { // stage 128 j-rows x 128 c fp16
        const ushort_t* g = xTh + (xb + j0 + grow)*CC + cc*128 + ghalf*64;
        ushort_t* d = xjh + grow*136 + ghalf*64;
        #pragma unroll
        for(int u = 0; u < 8; u++)
          *(uint4*)(d + u*8) = *(const uint4*)(g + u*8);
      }
      __syncthreads();
      #pragma unroll
      for(int k2 = 0; k2 < 4; k2++){
        const int coff = k2*32 + q*8;
        half8 bfrag[2];
        #pragma unroll
        for(int n2 = 0; n2 < 2; n2++){
          int jr = 32*w + 16*n2 + l15;
          bfrag[n2] = *(const half8*)(xjh + jr*136 + coff);
        }
        #pragma unroll
        for(int m = 0; m < 2; m++){
          #pragma unroll
          for(int n2 = 0; n2 < 2; n2++)
            acc[m][n2] = __builtin_amdgcn_mfma_f32_16x16x32_f16(afrag[m][cc*4+k2], bfrag[n2], acc[m][n2], 0, 0, 0);
        }
      }
    }
    // keys: key = 2*dot - ||xj||^2 ; C/D layout: col=lane&15, row=(lane>>4)*4+reg
    #pragma unroll
    for(int m = 0; m < 2; m++){
      int rbase = 16*m + q*4;
      #pragma unroll
      for(int n2 = 0; n2 < 2; n2++){
        int col = 32*w + 16*n2 + l15;
        float xv = xxs[col];
        #pragma unroll
        for(int r = 0; r < 4; r++)
          keybuf[rbase + r][col] = 2.0f*acc[m][n2][r] - xv;
      }
    }
    __syncthreads();
    // selection scan: each thread 16 keys of its row, private top-12
    {
      const float* kp = &keybuf[srow][ssub*16];
      #pragma unroll
      for(int e4 = 0; e4 < 4; e4++){
        float4 kv = *(const float4*)(kp + e4*4);
        float ks4[4] = {kv.x, kv.y, kv.z, kv.w};
        #pragma unroll
        for(int e = 0; e < 4; e++){
          float key = ks4[e];
          if(key > lv[11]){
            float cv = key; int ci = j0 + ssub*16 + e4*4 + e;
            #pragma unroll
            for(int k2 = 0; k2 < 12; k2++){
              if(cv > lv[k2]){ float tv = lv[k2]; int ti = li[k2]; lv[k2] = cv; li[k2] = ci; cv = tv; ci = ti; }
            }
          }
        }
      }
    }
  }

  __syncthreads();
  // merge: dump per-thread top-12 (overlays xjh region)
  #pragma unroll
  for(int k2 = 0; k2 < 12; k2++){
    mval[srow*96 + ssub*12 + k2] = lv[k2];
    midx[srow*96 + ssub*12 + k2] = li[k2];
  }
  if(t < 32) cnt[t] = 0;
  __syncthreads();
  // row leaders: fp32 top-11 of merged 96 + ambiguity check
  float l11[11]; int i11[11];
  if(t < 32){
    #pragma unroll
    for(int k2 = 0; k2 < 11; k2++){ l11[k2] = -3e38f; i11[k2] = -1; }
    for(int e = 0; e < 96; e++){
      float v = mval[t*96 + e];
      if(v > l11[10]){
        float cv = v; int ci = midx[t*96 + e];
        #pragma unroll
        for(int k2 = 0; k2 < 11; k2++){
          if(cv > l11[k2]){ float tv = l11[k2]; int ti = i11[k2]; l11[k2] = cv; i11[k2] = ci; cv = tv; ci = ti; }
        }
      }
    }
    ambs[t] = (l11[9] - l11[10]) <= (2.0f*DELTA) ? 1 : 0;
    taus[t] = l11[9] - 2.0f*DELTA;
  }
  __syncthreads();
  // exact fp64 recheck of window candidates for ambiguous rows (rare)
  if(ambs[srow]){
    float tau = taus[srow];
    const float* xip = xT + (xb + i0 + srow)*CC;
    for(int k2 = 0; k2 < 12; k2++){
      if(lv[k2] >= tau && li[k2] >= 0){
        int jg = li[k2];
        const float* xjp = xT + (xb + jg)*CC;
        double s = 0.0;
        for(int c = 0; c < CC; c += 4){
          float4 a4 = *(const float4*)(xip + c);
          float4 b4 = *(const float4*)(xjp + c);
          s += (double)a4.x*b4.x + (double)a4.y*b4.y + (double)a4.z*b4.z + (double)a4.w*b4.w;
        }
        double key64 = 2.0*s - xx[xb + jg];
        int pos = atomicAdd(&cnt[srow], 1);
        if(pos < 24){ dval[srow*24 + pos] = key64; didx[srow*24 + pos] = jg; }
      }
    }
  }
  __syncthreads();
  if(t < 32){
    size_t obase = ((size_t)b*NN + i0 + t)*KK;
    if(!ambs[t]){
      #pragma unroll
      for(int k2 = 0; k2 < 10; k2++) idxout[obase + k2] = i11[k2];
    } else {
      int n = cnt[t]; if(n > 24) n = 24;
      double bl[10]; int bi[10];
      #pragma unroll
      for(int k2 = 0; k2 < 10; k2++){ bl[k2] = -1e300; bi[k2] = 0x7fffffff; }
      for(int e = 0; e < n; e++){
        double v = dval[t*24 + e]; int j2 = didx[t*24 + e];
        if(v > bl[9] || (v == bl[9] && j2 < bi[9])){
          double cv = v; int ci = j2;
          #pragma unroll
          for(int k2 = 0; k2 < 10; k2++){
            if(cv > bl[k2] || (cv == bl[k2] && ci < bi[k2])){
              double tv = bl[k2]; int ti = bi[k2]; bl[k2] = cv; bi[k2] = ci; cv = tv; ci = ti;
            }
          }
        }
      }
      #pragma unroll
      for(int k2 = 0; k2 < 10; k2++) idxout[obase + k2] = bi[k2];
    }
  }
}

// ---------------- K3: pointwise convs: y1, y2(+sb1), t1=relu(tw1@x+tb1) ----------------
__global__ __launch_bounds__(128) void k_pointwise(
    const float* __restrict__ xT, const float* __restrict__ Wc,
    float* __restrict__ y1t, float* __restrict__ y2t, float* __restrict__ t1t){
  int b  = blockIdx.y;
  int n0 = blockIdx.x * 8;
  int o  = threadIdx.x;
  const float* w1 = Wc + SW1_O + o*512;
  const float* w2 = w1 + 256;
  const float* w3 = Wc + TW1_O + o*256;
  const float* xr = xT + ((size_t)b*NN + n0)*CC;
  float a1[8] = {0,0,0,0,0,0,0,0}, a2[8] = {0,0,0,0,0,0,0,0}, a3[8] = {0,0,0,0,0,0,0,0};
  for(int c = 0; c < 256; c += 4){
    float4 f1 = *(const float4*)(w1 + c);
    float4 f2 = *(const float4*)(w2 + c);
    float4 f3 = *(const float4*)(w3 + c);
    #pragma unroll
    for(int j = 0; j < 8; j++){
      float4 fx = *(const float4*)(xr + (size_t)j*CC + c);
      a1[j] += f1.x*fx.x + f1.y*fx.y + f1.z*fx.z + f1.w*fx.w;
      a2[j] += f2.x*fx.x + f2.y*fx.y + f2.z*fx.z + f2.w*fx.w;
      a3[j] += f3.x*fx.x + f3.y*fx.y + f3.z*fx.z + f3.w*fx.w;
    }
  }
  float b1 = Wc[SB1_O + o];
  float bt = Wc[TB1_O + o];
  #pragma unroll
  for(int j = 0; j < 8; j++){
    size_t r = ((size_t)b*NN + n0 + j)*WW + o;
    y1t[r] = a1[j];
    y2t[r] = a2[j] + b1;
    t1t[r] = fmaxf(a3[j] + bt, 0.f);
  }
}

// ---------------- K4: graph tail: gather -> sw2 -> sw3 GEMM -> max over k ----------------
__global__ __launch_bounds__(256) void k_s3max(
    const float* __restrict__ y1t, const float* __restrict__ y2t,
    const int* __restrict__ idx, const float* __restrict__ Wc,
    float* __restrict__ soutT){
  __shared__ ushort_t w3[128][132];
  __shared__ float U[40][132];
  __shared__ float y2s[4][128];
  __shared__ float pmax[8][128];
  __shared__ int idxs[40];
  int b  = blockIdx.z;
  int n0 = blockIdx.y * 4;
  int ch = blockIdx.x;
  int t  = threadIdx.x;
  #pragma unroll
  for(int e = 0; e < 16; e++){
    int qq = t + 256*e;
    int cl = qq >> 5;
    int c4 = (qq & 31) * 4;
    float4 v = *(const float4*)(Wc + SW3_O + ((size_t)(ch*128 + cl))*WW + c4);
    *(uint2*)&w3[cl][c4] = f4_to_bf4(v);
  }
  if(t < 40) idxs[t] = idx[((size_t)b*NN + n0 + t/10)*KK + (t%10)];
  #pragma unroll
  for(int e = 0; e < 2; e++){
    int lid = t + 256*e;
    int r = lid >> 7, o = lid & 127;
    y2s[r][o] = y2t[((size_t)b*NN + n0 + r)*WW + o];
  }
  __syncthreads();
  {
    int o = t & 127;
    int half = t >> 7;
    float4 wv = *(const float4*)(Wc + SW2_O + o*4);
    float b2 = Wc[SB2_O + o];
    int ob = o & ~3;
    for(int pp = 0; pp < 20; pp++){
      int p = pp*2 + half;
      int nl = p / 10;
      int j = idxs[p];
      const float4 yv  = *(const float4*)(y1t + ((size_t)b*NN + j)*WW + ob);
      const float4 y2v = *(const float4*)&y2s[nl][ob];
      float acc = b2;
      acc += wv.x*fmaxf(yv.x + y2v.x, 0.f);
      acc += wv.y*fmaxf(yv.y + y2v.y, 0.f);
      acc += wv.z*fmaxf(yv.z + y2v.z, 0.f);
      acc += wv.w*fmaxf(yv.w + y2v.w, 0.f);
      U[p][o] = fmaxf(acc, 0.f);
    }
  }
  __syncthreads();
  {
    int tc = t & 31;
    int tr = t >> 5;
    float acc[5][4];
    #pragma unroll
    for(int r = 0; r < 5; r++){ acc[r][0]=0.f; acc[r][1]=0.f; acc[r][2]=0.f; acc[r][3]=0.f; }
    for(int w = 0; w < 128; w += 4){
      float4 uv[5];
      #pragma unroll
      for(int r = 0; r < 5; r++) uv[r] = *(const float4*)&U[tr*5+r][w];
      float wf[4][4];
      #pragma unroll
      for(int g = 0; g < 4; g++){
        uint2 q = *(const uint2*)&w3[tc+32*g][w];
        wf[g][0]=bflo(q.x); wf[g][1]=bfhi(q.x); wf[g][2]=bflo(q.y); wf[g][3]=bfhi(q.y);
      }
      #pragma unroll
      for(int r = 0; r < 5; r++){
        #pragma unroll
        for(int g = 0; g < 4; g++)
          acc[r][g] += uv[r].x*wf[g][0] + uv[r].y*wf[g][1] + uv[r].z*wf[g][2] + uv[r].w*wf[g][3];
      }
    }
    #pragma unroll
    for(int g = 0; g < 4; g++){
      float m = acc[0][g];
      #pragma unroll
      for(int r = 1; r < 5; r++) m = fmaxf(m, acc[r][g]);
      pmax[tr][tc+32*g] = m;
    }
  }
  __syncthreads();
  #pragma unroll
  for(int e = 0; e < 2; e++){
    int lid = t + 256*e;
    int g = lid >> 7;
    int col = lid & 127;
    float v = fmaxf(pmax[2*g][col], pmax[2*g+1][col]) + Wc[SB3_O + ch*128 + col];
    soutT[((size_t)b*NN + n0+g)*CC + ch*128 + col] = v;
  }
}

// ---------------- K5: temporal tail: grouped conv3 -> tw3 GEMM; ACCUMULATES into soutT ----------------
__global__ __launch_bounds__(256) void k_tout(
    const float* __restrict__ t1t, const float* __restrict__ Wc,
    float* __restrict__ soutT){
  __shared__ float t2s[64][132];
  __shared__ ushort_t w3s[64][132];
  int b  = blockIdx.z;
  int n0 = blockIdx.y * 64;
  int cb = blockIdx.x * 64;
  int t  = threadIdx.x;
  {
    int o = t & 127;
    int rbase = t >> 7;
    float w2v[12];
    #pragma unroll
    for(int z = 0; z < 12; z++) w2v[z] = Wc[TW2_O + o*12 + z];
    float bv = Wc[TB2_O + o];
    int ob = o & ~3;
    for(int e = 0; e < 32; e++){
      int r = rbase + 2*e;
      int n = n0 + r;
      float acc = bv;
      #pragma unroll
      for(int d = 0; d < 3; d++){
        int nn2 = n + d - 1;
        if(nn2 >= 0 && nn2 < NN){
          float4 tv = *(const float4*)(t1t + ((size_t)b*NN + nn2)*WW + ob);
          acc += w2v[0*3+d]*tv.x + w2v[1*3+d]*tv.y + w2v[2*3+d]*tv.z + w2v[3*3+d]*tv.w;
        }
      }
      t2s[r][o] = fmaxf(acc, 0.f);
    }
  }
  #pragma unroll
  for(int e = 0; e < 8; e++){
    int qq = t + 256*e;
    int cl = qq >> 5;
    int c4 = (qq & 31) * 4;
    float4 v = *(const float4*)(Wc + TW3_O + ((size_t)(cb + cl))*WW + c4);
    *(uint2*)&w3s[cl][c4] = f4_to_bf4(v);
  }
  __syncthreads();
  int tr = t >> 4, tc = t & 15;
  float acc[4][4];
  #pragma unroll
  for(int r = 0; r < 4; r++){ acc[r][0]=0.f; acc[r][1]=0.f; acc[r][2]=0.f; acc[r][3]=0.f; }
  for(int w = 0; w < 128; w += 4){
    float4 uv[4];
    #pragma unroll
    for(int r = 0; r < 4; r++) uv[r] = *(const float4*)&t2s[tr+16*r][w];
    float wf[4][4];
    #pragma unroll
    for(int g = 0; g < 4; g++){
      uint2 q = *(const uint2*)&w3s[tc+16*g][w];
      wf[g][0]=bflo(q.x); wf[g][1]=bfhi(q.x); wf[g][2]=bflo(q.y); wf[g][3]=bfhi(q.y);
    }
    #pragma unroll
    for(int r = 0; r < 4; r++){
      #pragma unroll
      for(int g = 0; g < 4; g++)
        acc[r][g] += uv[r].x*wf[g][0] + uv[r].y*wf[g][1] + uv[r].z*wf[g][2] + uv[r].w*wf[g][3];
    }
  }
  #pragma unroll
  for(int g = 0; g < 4; g++){
    float bv = Wc[TB3_O + cb + tc + 16*g];
    #pragma unroll
    for(int r = 0; r < 4; r++){
      size_t off = ((size_t)b*NN + n0 + tr + 16*r)*CC + cb + tc + 16*g;
      soutT[off] = soutT[off] + acc[r][g] + bv;   // sout + tout combined
    }
  }
}

// ---------------- K6: out = relu(comb (transposed) + x), dtype per flag ----------------
__global__ void k_final(const float* __restrict__ soutT, const void* __restrict__ xraw,
                        const int* __restrict__ flag, void* __restrict__ outraw){
  __shared__ float tile[32][33];
  int isf = flag[0];
  int b = blockIdx.z;
  int n0 = blockIdx.x*32, c0 = blockIdx.y*32;
  int tx = threadIdx.x, ty = threadIdx.y;
  #pragma unroll
  for(int r = 0; r < 4; r++){
    int n = n0 + ty + 8*r;
    size_t off = ((size_t)b*NN + n)*CC + c0 + tx;
    tile[ty+8*r][tx] = soutT[off];
  }
  __syncthreads();
  #pragma unroll
  for(int r = 0; r < 4; r++){
    int c = c0 + ty + 8*r;
    size_t off = ((size_t)b*CC + c)*NN + n0 + tx;
    float xv = isf ? ((const float*)xraw)[off] : bfs(((const ushort_t*)xraw)[off]);
    float v = fmaxf(tile[tx][ty+8*r] + xv, 0.f);
    if(isf) ((float*)outraw)[off] = v;
    else    ((ushort_t*)outraw)[off] = f2bf16(v);
  }
}

extern "C" void kernel_launch(void* const* d_in, const int* in_sizes, int n_in,
                              void* d_out, int out_size, void* d_ws, size_t ws_size,
                              hipStream_t stream){
  char* ws = (char*)d_ws;
  // workspace layout (bytes)
  int*      flag  = (int*)     (ws + 0);
  float*    Wc    = (float*)   (ws + 256);          //    667,648
  float*    xT    = (float*)   (ws + 1048576);      // 33,554,432
  double*   xx    = (double*)  (ws + 34603008);     //    262,144
  float*    xxf   = (float*)   (ws + 34865152);     //    131,072
  int*      idx   = (int*)     (ws + 34996224);     //  1,310,720
  float*    y1t   = (float*)   (ws + 36306944);     // 16,777,216
  float*    y2t   = (float*)   (ws + 53084160);     // 16,777,216
  float*    t1t   = (float*)   (ws + 69861376);     // 16,777,216
  float*    soutT = (float*)   (ws + 86638592);     // 33,554,432
  ushort_t* xTh   = (ushort_t*)(ws + 120193024);    // 16,777,216  (end 136,970,240)

  k_detect<<<1, 256, 0, stream>>>(d_in[0], flag);
  k_convw<<<dim3(64,12), 256, 0, stream>>>(d_in[1], d_in[2], d_in[3], d_in[4], d_in[5], d_in[6],
                                           d_in[7], d_in[8], d_in[9], d_in[10], d_in[11], d_in[12],
                                           Wc, flag);
  k_convx<<<dim3(64,8,16), dim3(32,8), 0, stream>>>(d_in[0], flag, xT, xTh);
  k_norms<<<dim3(8192), dim3(256), 0, stream>>>(xT, xx, xxf);
  k_knn<<<dim3(16,64), dim3(256), 0, stream>>>(xTh, xT, xx, xxf, idx);
  k_pointwise<<<dim3(256,16), dim3(128), 0, stream>>>(xT, Wc, y1t, y2t, t1t);
  k_s3max<<<dim3(2,512,16), dim3(256), 0, stream>>>(y1t, y2t, idx, Wc, soutT);
  k_tout<<<dim3(4,32,16), dim3(256), 0, stream>>>(t1t, Wc, soutT);
  k_final<<<dim3(64,8,16), dim3(32,8), 0, stream>>>(soutT, d_in[0], flag, d_out);
}

// Round 6
// 1128.637 us; speedup vs baseline: 2.7839x; 1.4150x over previous
//
#include <hip/hip_runtime.h>
#include <hip/hip_bf16.h>
#include <stdint.h>

#define BB 16
#define CC 256
#define NN 2048
#define KK 10
#define WW 128
#define DELTA 0.05f

typedef unsigned short ushort_t;
typedef __attribute__((ext_vector_type(8))) _Float16 half8;
typedef __attribute__((ext_vector_type(8))) short short8;
typedef __attribute__((ext_vector_type(4))) float f32x4;

// converted-weight table offsets (fp32 elements)
#define TW1_O 0
#define TB1_O 32768
#define TW2_O 32896
#define TB2_O 34432
#define TW3_O 34560
#define TB3_O 67328
#define SW1_O 67584
#define SB1_O 133120
#define SW2_O 133248
#define SB2_O 133760
#define SW3_O 133888
#define SB3_O 166656

__device__ __forceinline__ float bflo(unsigned p){ union{unsigned u; float f;} v; v.u = p << 16; return v.f; }
__device__ __forceinline__ float bfhi(unsigned p){ union{unsigned u; float f;} v; v.u = p & 0xffff0000u; return v.f; }
__device__ __forceinline__ float bfs(ushort_t u){ union{unsigned u; float f;} v; v.u = ((unsigned)u) << 16; return v.f; }
__device__ __forceinline__ ushort_t f2bf16(float f){
  __hip_bfloat16 h = __float2bfloat16(f);
  return *reinterpret_cast<ushort_t*>(&h);
}
__device__ __forceinline__ uint2 f4_to_bf4(float4 v){
  uint2 r;
  r.x = (unsigned)f2bf16(v.x) | ((unsigned)f2bf16(v.y) << 16);
  r.y = (unsigned)f2bf16(v.z) | ((unsigned)f2bf16(v.w) << 16);
  return r;
}
__device__ __forceinline__ float max4(f32x4 v){ return fmaxf(fmaxf(v[0],v[1]), fmaxf(v[2],v[3])); }

// ---------------- D0: detect input dtype ----------------
__global__ void k_detect(const void* __restrict__ xraw, int* __restrict__ flag){
  __shared__ float red[256];
  int t = threadIdx.x;
  const ushort_t* p = (const ushort_t*)xraw;
  float m = 0.f;
  for(int i = t; i < 1024; i += 256){
    float v = bfs(p[i]);
    v = fabsf(v);
    if(!(v < 1e30f)) v = 1e30f;
    m = fmaxf(m, v);
  }
  red[t] = m; __syncthreads();
  for(int s = 128; s > 0; s >>= 1){ if(t < s) red[t] = fmaxf(red[t], red[t+s]); __syncthreads(); }
  if(t == 0) flag[0] = (red[0] > 1e3f) ? 1 : 0;   // 1 => inputs are fp32
}

// ---------------- D1: convert all weights/biases to fp32 table ----------------
__global__ void k_convw(const void* p0, const void* p1, const void* p2, const void* p3,
                        const void* p4, const void* p5, const void* p6, const void* p7,
                        const void* p8, const void* p9, const void* p10, const void* p11,
                        float* __restrict__ dst, const int* __restrict__ flag){
  const int counts[12] = {32768,128,1536,128,32768,256,65536,128,512,128,32768,256};
  const int offs[12]   = {TW1_O,TB1_O,TW2_O,TB2_O,TW3_O,TB3_O,SW1_O,SB1_O,SW2_O,SB2_O,SW3_O,SB3_O};
  int a = blockIdx.y;
  const void* src;
  switch(a){
    case 0: src=p0; break; case 1: src=p1; break; case 2: src=p2; break;
    case 3: src=p3; break; case 4: src=p4; break; case 5: src=p5; break;
    case 6: src=p6; break; case 7: src=p7; break; case 8: src=p8; break;
    case 9: src=p9; break; case 10: src=p10; break; default: src=p11; break;
  }
  int cnt = counts[a], off = offs[a];
  int isf = flag[0];
  for(int i = blockIdx.x*256 + threadIdx.x; i < cnt; i += gridDim.x*256){
    float v = isf ? ((const float*)src)[i] : bfs(((const ushort_t*)src)[i]);
    dst[off + i] = v;
  }
}

// ---------------- D2: canonicalize x -> xT fp32 (B,N,C) + fp16 copy ----------------
__global__ void k_convx(const void* __restrict__ xraw, const int* __restrict__ flag,
                        float* __restrict__ xT, ushort_t* __restrict__ xTh){
  __shared__ float tile[32][33];
  int isf = flag[0];
  int b = blockIdx.z;
  int n0 = blockIdx.x * 32;
  int c0 = blockIdx.y * 32;
  int tx = threadIdx.x, ty = threadIdx.y;
  #pragma unroll
  for(int r = 0; r < 4; r++){
    int c = c0 + ty + r*8;
    size_t off = ((size_t)b*CC + c)*NN + n0 + tx;
    float v = isf ? ((const float*)xraw)[off] : bfs(((const ushort_t*)xraw)[off]);
    tile[ty + r*8][tx] = v;
  }
  __syncthreads();
  #pragma unroll
  for(int r = 0; r < 4; r++){
    int n = n0 + ty + r*8;
    size_t off = ((size_t)b*NN + n)*CC + c0 + tx;
    float v = tile[tx][ty + r*8];
    xT[off] = v;
    _Float16 h = (_Float16)v;
    xTh[off] = *reinterpret_cast<ushort_t*>(&h);
  }
}

// ---------------- K1: row norms (fp64 + fp32 copy) ----------------
__global__ void k_norms(const float* __restrict__ xT, double* __restrict__ xx,
                        float* __restrict__ xxf){
  int row = blockIdx.x*4 + (threadIdx.x >> 6);
  int lane = threadIdx.x & 63;
  float4 q = *(const float4*)(xT + (size_t)row*CC + lane*4);
  double s = (double)q.x*q.x + (double)q.y*q.y + (double)q.z*q.z + (double)q.w*q.w;
  #pragma unroll
  for(int off = 32; off > 0; off >>= 1) s += __shfl_down(s, off);
  if(lane == 0){ xx[row] = s; xxf[row] = (float)s; }
}

// ---------------- K2: kNN — fp16 MFMA screen, 64-row j-chunks, 4 blocks/CU ----------------
// grid (B, N/32); block 256 (4 waves). i-tile 32 rows; j-chunks of 64, staged 128c x2.
__global__ __launch_bounds__(256, 4) void k_knn(
    const ushort_t* __restrict__ xTh, const float* __restrict__ xT,
    const double* __restrict__ xx, const float* __restrict__ xxf,
    int* __restrict__ idxout){
  __shared__ char smem[33792];
  ushort_t* xjh   = (ushort_t*)smem;          // [64][136] fp16  (17408 B)
  float*    keybuf= (float*)(smem + 17408);   // [32][68]        ( 8704 B)
  float*    xxs   = (float*)(smem + 26112);   // [64]            (  256 B)
  float*    mval  = (float*)smem;             // [32][96] overlay(12288 B)
  int*      midx  = (int*)(smem + 12288);     // [32][96]        (12288 B)
  double*   dval  = (double*)(smem + 24576);  // [32][24]        ( 6144 B)
  int*      didx  = (int*)(smem + 30720);     // [32][24]        ( 3072 B)
  __shared__ float taus[32];
  __shared__ int   ambs[32];
  __shared__ int   cnt[32];

  const int t    = threadIdx.x;
  const int lane = t & 63;
  const int w    = t >> 6;
  const int b    = blockIdx.x;
  const int i0   = blockIdx.y * 32;
  const size_t xb = (size_t)b * NN;
  const int l15  = lane & 15;
  const int q    = lane >> 4;

  // preload A fragments (Xi rows i0..i0+31), fp16, all K=256: 64 VGPRs
  half8 afrag[2][8];
  #pragma unroll
  for(int m = 0; m < 2; m++){
    const ushort_t* pa = xTh + (xb + i0 + 16*m + l15)*CC + q*8;
    #pragma unroll
    for(int ks = 0; ks < 8; ks++)
      afrag[m][ks] = *(const half8*)(pa + ks*32);
  }

  float lv[12]; int li[12];
  #pragma unroll
  for(int k2 = 0; k2 < 12; k2++){ lv[k2] = -3e38f; li[k2] = -1; }

  const int srow = t >> 3;   // selection row 0..31
  const int ssub = t & 7;
  const int grow = t >> 2;   // staging row 0..63
  const int gqtr = t & 3;

  for(int jc = 0; jc < 32; jc++){
    const int j0 = jc * 64;
    f32x4 acc[2];
    acc[0] = (f32x4){0.f,0.f,0.f,0.f};
    acc[1] = (f32x4){0.f,0.f,0.f,0.f};

    #pragma unroll
    for(int cc = 0; cc < 2; cc++){
      __syncthreads();
      if(cc == 0 && t < 64) xxs[t] = xxf[xb + j0 + t];
      { // stage 64 j-rows x 128 c fp16
        const ushort_t* g = xTh + (xb + j0 + grow)*CC + cc*128 + gqtr*32;
        ushort_t* d = xjh + grow*136 + gqtr*32;
        #pragma unroll
        for(int u = 0; u < 4; u++)
          *(uint4*)(d + u*8) = *(const uint4*)(g + u*8);
      }
      __syncthreads();
      #pragma unroll
      for(int k2 = 0; k2 < 4; k2++){
        const int jr = w*16 + l15;
        half8 bfrag = *(const half8*)(xjh + jr*136 + k2*32 + q*8);
        #pragma unroll
        for(int m = 0; m < 2; m++)
          acc[m] = __builtin_amdgcn_mfma_f32_16x16x32_f16(afrag[m][cc*4+k2], bfrag, acc[m], 0, 0, 0);
      }
    }
    // keys: key = 2*dot - ||xj||^2 ; C/D layout: col=lane&15, row=(lane>>4)*4+reg
    {
      int col = w*16 + l15;
      float xv = xxs[col];
      #pragma unroll
      for(int m = 0; m < 2; m++){
        int rbase = 16*m + q*4;
        #pragma unroll
        for(int r = 0; r < 4; r++)
          keybuf[(rbase + r)*68 + col] = 2.0f*acc[m][r] - xv;
      }
    }
    __syncthreads();
    // selection scan: each thread 8 keys of its row, private top-12
    {
      const float* kp = keybuf + srow*68 + ssub*8;
      #pragma unroll
      for(int e4 = 0; e4 < 2; e4++){
        float4 kv = *(const float4*)(kp + e4*4);
        float ks4[4] = {kv.x, kv.y, kv.z, kv.w};
        #pragma unroll
        for(int e = 0; e < 4; e++){
          float key = ks4[e];
          if(key > lv[11]){
            float cv = key; int ci = j0 + ssub*8 + e4*4 + e;
            #pragma unroll
            for(int k2 = 0; k2 < 12; k2++){
              if(cv > lv[k2]){ float tv = lv[k2]; int ti = li[k2]; lv[k2] = cv; li[k2] = ci; cv = tv; ci = ti; }
            }
          }
        }
      }
    }
  }

  __syncthreads();
  // merge: dump per-thread top-12 (overlays staging region)
  #pragma unroll
  for(int k2 = 0; k2 < 12; k2++){
    mval[srow*96 + ssub*12 + k2] = lv[k2];
    midx[srow*96 + ssub*12 + k2] = li[k2];
  }
  if(t < 32) cnt[t] = 0;
  __syncthreads();
  // row leaders: fp32 top-11 of merged 96 + ambiguity check
  float l11[11]; int i11[11];
  if(t < 32){
    #pragma unroll
    for(int k2 = 0; k2 < 11; k2++){ l11[k2] = -3e38f; i11[k2] = -1; }
    for(int e = 0; e < 96; e++){
      float v = mval[t*96 + e];
      if(v > l11[10]){
        float cv = v; int ci = midx[t*96 + e];
        #pragma unroll
        for(int k2 = 0; k2 < 11; k2++){
          if(cv > l11[k2]){ float tv = l11[k2]; int ti = i11[k2]; l11[k2] = cv; i11[k2] = ci; cv = tv; ci = ti; }
        }
      }
    }
    ambs[t] = (l11[9] - l11[10]) <= (2.0f*DELTA) ? 1 : 0;
    taus[t] = l11[9] - 2.0f*DELTA;
  }
  __syncthreads();
  // exact fp64 recheck of window candidates for ambiguous rows (rare)
  if(ambs[srow]){
    float tau = taus[srow];
    const float* xip = xT + (xb + i0 + srow)*CC;
    for(int k2 = 0; k2 < 12; k2++){
      if(lv[k2] >= tau && li[k2] >= 0){
        int jg = li[k2];
        const float* xjp = xT + (xb + jg)*CC;
        double s = 0.0;
        for(int c = 0; c < CC; c += 4){
          float4 a4 = *(const float4*)(xip + c);
          float4 b4 = *(const float4*)(xjp + c);
          s += (double)a4.x*b4.x + (double)a4.y*b4.y + (double)a4.z*b4.z + (double)a4.w*b4.w;
        }
        double key64 = 2.0*s - xx[xb + jg];
        int pos = atomicAdd(&cnt[srow], 1);
        if(pos < 24){ dval[srow*24 + pos] = key64; didx[srow*24 + pos] = jg; }
      }
    }
  }
  __syncthreads();
  if(t < 32){
    size_t obase = ((size_t)b*NN + i0 + t)*KK;
    if(!ambs[t]){
      #pragma unroll
      for(int k2 = 0; k2 < 10; k2++) idxout[obase + k2] = i11[k2];
    } else {
      int n = cnt[t]; if(n > 24) n = 24;
      double bl[10]; int bi[10];
      #pragma unroll
      for(int k2 = 0; k2 < 10; k2++){ bl[k2] = -1e300; bi[k2] = 0x7fffffff; }
      for(int e = 0; e < n; e++){
        double v = dval[t*24 + e]; int j2 = didx[t*24 + e];
        if(v > bl[9] || (v == bl[9] && j2 < bi[9])){
          double cv = v; int ci = j2;
          #pragma unroll
          for(int k2 = 0; k2 < 10; k2++){
            if(cv > bl[k2] || (cv == bl[k2] && ci < bi[k2])){
              double tv = bl[k2]; int ti = bi[k2]; bl[k2] = cv; bi[k2] = ci; cv = tv; ci = ti;
            }
          }
        }
      }
      #pragma unroll
      for(int k2 = 0; k2 < 10; k2++) idxout[obase + k2] = bi[k2];
    }
  }
}

// ---------------- K3: pointwise convs: y1, y2(+sb1), t1=relu(tw1@x+tb1) ----------------
__global__ __launch_bounds__(128) void k_pointwise(
    const float* __restrict__ xT, const float* __restrict__ Wc,
    float* __restrict__ y1t, float* __restrict__ y2t, float* __restrict__ t1t){
  int b  = blockIdx.y;
  int n0 = blockIdx.x * 8;
  int o  = threadIdx.x;
  const float* w1 = Wc + SW1_O + o*512;
  const float* w2 = w1 + 256;
  const float* w3 = Wc + TW1_O + o*256;
  const float* xr = xT + ((size_t)b*NN + n0)*CC;
  float a1[8] = {0,0,0,0,0,0,0,0}, a2[8] = {0,0,0,0,0,0,0,0}, a3[8] = {0,0,0,0,0,0,0,0};
  for(int c = 0; c < 256; c += 4){
    float4 f1 = *(const float4*)(w1 + c);
    float4 f2 = *(const float4*)(w2 + c);
    float4 f3 = *(const float4*)(w3 + c);
    #pragma unroll
    for(int j = 0; j < 8; j++){
      float4 fx = *(const float4*)(xr + (size_t)j*CC + c);
      a1[j] += f1.x*fx.x + f1.y*fx.y + f1.z*fx.z + f1.w*fx.w;
      a2[j] += f2.x*fx.x + f2.y*fx.y + f2.z*fx.z + f2.w*fx.w;
      a3[j] += f3.x*fx.x + f3.y*fx.y + f3.z*fx.z + f3.w*fx.w;
    }
  }
  float b1 = Wc[SB1_O + o];
  float bt = Wc[TB1_O + o];
  #pragma unroll
  for(int j = 0; j < 8; j++){
    size_t r = ((size_t)b*NN + n0 + j)*WW + o;
    y1t[r] = a1[j];
    y2t[r] = a2[j] + b1;
    t1t[r] = fmaxf(a3[j] + bt, 0.f);
  }
}

// ---------------- K4: graph tail v2 — MFMA GEMM + register max-over-k ----------------
// grid (2 ch-halves, N/8, B); block 256 (4 waves). 8 n-points -> 80 U-rows = 5 m-tiles.
__global__ __launch_bounds__(256, 3) void k_s3max(
    const float* __restrict__ y1t, const float* __restrict__ y2t,
    const int* __restrict__ idx, const float* __restrict__ Wc,
    float* __restrict__ soutT){
  __shared__ ushort_t w3s[64][136];   // bf16, rows = out-col (64 per half), cols = k
  __shared__ ushort_t Us[80][136];    // bf16, rows = p (n*10+k), cols = k(=W chan)
  __shared__ float y2s[8][128];
  __shared__ int idxs[80];
  int b  = blockIdx.z;
  int n0 = blockIdx.y * 8;
  int ch = blockIdx.x;
  int t  = threadIdx.x;
  const int lane = t & 63, w = t >> 6, l15 = lane & 15, q = lane >> 4;

  if(t < 80) idxs[t] = idx[((size_t)b*NN + n0 + t/10)*KK + (t%10)];
  {
    int r = t >> 5, g = t & 31;
    *(float4*)&y2s[r][g*4] = *(const float4*)(y2t + ((size_t)b*NN + n0 + r)*WW + g*4);
  }
  // per-thread group weights (sw2) for col-group g2
  const int g2 = t & 31;
  float4 w2r[4];
  #pragma unroll
  for(int e = 0; e < 4; e++) w2r[e] = *(const float4*)(Wc + SW2_O + (g2*4+e)*4);
  const float4 b2v = *(const float4*)(Wc + SB2_O + g2*4);
  __syncthreads();

  // build U: 10 iters x 8 p-rows; thread (pr = t>>5, g2) produces 4 cols
  {
    int pr = t >> 5;
    #pragma unroll 2
    for(int it = 0; it < 10; it++){
      int p = it*8 + pr;
      int np = p / 10;
      int j = idxs[p];
      float4 yv = *(const float4*)(y1t + ((size_t)b*NN + j)*WW + g2*4);
      float4 y2v = *(const float4*)&y2s[np][g2*4];
      float v0 = fmaxf(yv.x + y2v.x, 0.f);
      float v1 = fmaxf(yv.y + y2v.y, 0.f);
      float v2 = fmaxf(yv.z + y2v.z, 0.f);
      float v3 = fmaxf(yv.w + y2v.w, 0.f);
      float4 u;
      u.x = fmaxf(b2v.x + w2r[0].x*v0 + w2r[0].y*v1 + w2r[0].z*v2 + w2r[0].w*v3, 0.f);
      u.y = fmaxf(b2v.y + w2r[1].x*v0 + w2r[1].y*v1 + w2r[1].z*v2 + w2r[1].w*v3, 0.f);
      u.z = fmaxf(b2v.z + w2r[2].x*v0 + w2r[2].y*v1 + w2r[2].z*v2 + w2r[2].w*v3, 0.f);
      u.w = fmaxf(b2v.w + w2r[3].x*v0 + w2r[3].y*v1 + w2r[3].z*v2 + w2r[3].w*v3, 0.f);
      *(uint2*)&Us[p][g2*4] = f4_to_bf4(u);
    }
  }

  #pragma unroll
  for(int half = 0; half < 2; half++){
    if(half) __syncthreads();    // protect w3s from previous MFMA reads
    { // stage w3 half: 64 out-cols x 128 k, fp32 -> bf16
      int row = t >> 2, qtr = t & 3;
      const float* src = Wc + SW3_O + ((size_t)(ch*128 + half*64 + row))*WW + qtr*32;
      #pragma unroll
      for(int u = 0; u < 8; u++){
        float4 v = *(const float4*)(src + u*4);
        *(uint2*)&w3s[row][qtr*32 + u*4] = f4_to_bf4(v);
      }
    }
    __syncthreads();
    // MFMA: wave w -> n-tile w (16 out-cols); 5 m-tiles x 4 k-steps
    f32x4 a5[5];
    #pragma unroll
    for(int mt = 0; mt < 5; mt++) a5[mt] = (f32x4){0.f,0.f,0.f,0.f};
    #pragma unroll
    for(int k = 0; k < 4; k++){
      short8 bfrag = *(const short8*)(&w3s[w*16 + l15][k*32 + q*8]);
      #pragma unroll
      for(int mt = 0; mt < 5; mt++){
        short8 af = *(const short8*)(&Us[mt*16 + l15][k*32 + q*8]);
        a5[mt] = __builtin_amdgcn_mfma_f32_16x16x32_bf16(af, bfrag, a5[mt], 0, 0, 0);
      }
    }
    // register max-over-k: lane holds rows p = mt*16 + 4q + r, col = half*64 + w*16 + l15
    float gm[8];
    #pragma unroll
    for(int g = 0; g < 8; g++) gm[g] = -3e38f;
    if(q == 0){
      gm[0]=max4(a5[0]); gm[1]=max4(a5[1]); gm[3]=max4(a5[2]);
      gm[4]=fmaxf(a5[3][0],a5[3][1]); gm[5]=fmaxf(a5[3][2],a5[3][3]); gm[6]=max4(a5[4]);
    } else if(q == 1){
      gm[0]=max4(a5[0]); gm[2]=max4(a5[1]); gm[3]=max4(a5[2]); gm[5]=max4(a5[3]);
      gm[6]=fmaxf(a5[4][0],a5[4][1]); gm[7]=fmaxf(a5[4][2],a5[4][3]);
    } else if(q == 2){
      gm[0]=fmaxf(a5[0][0],a5[0][1]); gm[1]=fmaxf(a5[0][2],a5[0][3]);
      gm[2]=max4(a5[1]); gm[4]=max4(a5[2]); gm[5]=max4(a5[3]); gm[7]=max4(a5[4]);
    } else {
      gm[1]=max4(a5[0]); gm[2]=fmaxf(a5[1][0],a5[1][1]); gm[3]=fmaxf(a5[1][2],a5[1][3]);
      gm[4]=max4(a5[2]); gm[6]=max4(a5[3]); gm[7]=max4(a5[4]);
    }
    #pragma unroll
    for(int g = 0; g < 8; g++){
      float v = gm[g];
      v = fmaxf(v, __shfl_xor(v, 16));
      v = fmaxf(v, __shfl_xor(v, 32));
      gm[g] = v;
    }
    int col = ch*128 + half*64 + w*16 + l15;
    float bias = Wc[SB3_O + col];
    soutT[((size_t)b*NN + n0 + 2*q)*CC + col]     = gm[2*q] + bias;
    soutT[((size_t)b*NN + n0 + 2*q + 1)*CC + col] = gm[2*q+1] + bias;
  }
}

// ---------------- K5: temporal tail: grouped conv3 -> tw3 GEMM; ACCUMULATES into soutT ----------------
__global__ __launch_bounds__(256) void k_tout(
    const float* __restrict__ t1t, const float* __restrict__ Wc,
    float* __restrict__ soutT){
  __shared__ float t2s[64][132];
  __shared__ ushort_t w3s[64][132];
  int b  = blockIdx.z;
  int n0 = blockIdx.y * 64;
  int cb = blockIdx.x * 64;
  int t  = threadIdx.x;
  {
    int o = t & 127;
    int rbase = t >> 7;
    float w2v[12];
    #pragma unroll
    for(int z = 0; z < 12; z++) w2v[z] = Wc[TW2_O + o*12 + z];
    float bv = Wc[TB2_O + o];
    int ob = o & ~3;
    for(int e = 0; e < 32; e++){
      int r = rbase + 2*e;
      int n = n0 + r;
      float acc = bv;
      #pragma unroll
      for(int d = 0; d < 3; d++){
        int nn2 = n + d - 1;
        if(nn2 >= 0 && nn2 < NN){
          float4 tv = *(const float4*)(t1t + ((size_t)b*NN + nn2)*WW + ob);
          acc += w2v[0*3+d]*tv.x + w2v[1*3+d]*tv.y + w2v[2*3+d]*tv.z + w2v[3*3+d]*tv.w;
        }
      }
      t2s[r][o] = fmaxf(acc, 0.f);
    }
  }
  #pragma unroll
  for(int e = 0; e < 8; e++){
    int qq = t + 256*e;
    int cl = qq >> 5;
    int c4 = (qq & 31) * 4;
    float4 v = *(const float4*)(Wc + TW3_O + ((size_t)(cb + cl))*WW + c4);
    *(uint2*)&w3s[cl][c4] = f4_to_bf4(v);
  }
  __syncthreads();
  int tr = t >> 4, tc = t & 15;
  float acc[4][4];
  #pragma unroll
  for(int r = 0; r < 4; r++){ acc[r][0]=0.f; acc[r][1]=0.f; acc[r][2]=0.f; acc[r][3]=0.f; }
  for(int w = 0; w < 128; w += 4){
    float4 uv[4];
    #pragma unroll
    for(int r = 0; r < 4; r++) uv[r] = *(const float4*)&t2s[tr+16*r][w];
    float wf[4][4];
    #pragma unroll
    for(int g = 0; g < 4; g++){
      uint2 q = *(const uint2*)&w3s[tc+16*g][w];
      wf[g][0]=bflo(q.x); wf[g][1]=bfhi(q.x); wf[g][2]=bflo(q.y); wf[g][3]=bfhi(q.y);
    }
    #pragma unroll
    for(int r = 0; r < 4; r++){
      #pragma unroll
      for(int g = 0; g < 4; g++)
        acc[r][g] += uv[r].x*wf[g][0] + uv[r].y*wf[g][1] + uv[r].z*wf[g][2] + uv[r].w*wf[g][3];
    }
  }
  #pragma unroll
  for(int g = 0; g < 4; g++){
    float bv = Wc[TB3_O + cb + tc + 16*g];
    #pragma unroll
    for(int r = 0; r < 4; r++){
      size_t off = ((size_t)b*NN + n0 + tr + 16*r)*CC + cb + tc + 16*g;
      soutT[off] = soutT[off] + acc[r][g] + bv;   // sout + tout combined
    }
  }
}

// ---------------- K6: out = relu(comb (transposed) + x), dtype per flag ----------------
__global__ void k_final(const float* __restrict__ soutT, const void* __restrict__ xraw,
                        const int* __restrict__ flag, void* __restrict__ outraw){
  __shared__ float tile[32][33];
  int isf = flag[0];
  int b = blockIdx.z;
  int n0 = blockIdx.x*32, c0 = blockIdx.y*32;
  int tx = threadIdx.x, ty = threadIdx.y;
  #pragma unroll
  for(int r = 0; r < 4; r++){
    int n = n0 + ty + 8*r;
    size_t off = ((size_t)b*NN + n)*CC + c0 + tx;
    tile[ty+8*r][tx] = soutT[off];
  }
  __syncthreads();
  #pragma unroll
  for(int r = 0; r < 4; r++){
    int c = c0 + ty + 8*r;
    size_t off = ((size_t)b*CC + c)*NN + n0 + tx;
    float xv = isf ? ((const float*)xraw)[off] : bfs(((const ushort_t*)xraw)[off]);
    float v = fmaxf(tile[tx][ty+8*r] + xv, 0.f);
    if(isf) ((float*)outraw)[off] = v;
    else    ((ushort_t*)outraw)[off] = f2bf16(v);
  }
}

extern "C" void kernel_launch(void* const* d_in, const int* in_sizes, int n_in,
                              void* d_out, int out_size, void* d_ws, size_t ws_size,
                              hipStream_t stream){
  char* ws = (char*)d_ws;
  // workspace layout (bytes)
  int*      flag  = (int*)     (ws + 0);
  float*    Wc    = (float*)   (ws + 256);          //    667,648
  float*    xT    = (float*)   (ws + 1048576);      // 33,554,432
  double*   xx    = (double*)  (ws + 34603008);     //    262,144
  float*    xxf   = (float*)   (ws + 34865152);     //    131,072
  int*      idx   = (int*)     (ws + 34996224);     //  1,310,720
  float*    y1t   = (float*)   (ws + 36306944);     // 16,777,216
  float*    y2t   = (float*)   (ws + 53084160);     // 16,777,216
  float*    t1t   = (float*)   (ws + 69861376);     // 16,777,216
  float*    soutT = (float*)   (ws + 86638592);     // 33,554,432
  ushort_t* xTh   = (ushort_t*)(ws + 120193024);    // 16,777,216  (end 136,970,240)

  k_detect<<<1, 256, 0, stream>>>(d_in[0], flag);
  k_convw<<<dim3(64,12), 256, 0, stream>>>(d_in[1], d_in[2], d_in[3], d_in[4], d_in[5], d_in[6],
                                           d_in[7], d_in[8], d_in[9], d_in[10], d_in[11], d_in[12],
                                           Wc, flag);
  k_convx<<<dim3(64,8,16), dim3(32,8), 0, stream>>>(d_in[0], flag, xT, xTh);
  k_norms<<<dim3(8192), dim3(256), 0, stream>>>(xT, xx, xxf);
  k_knn<<<dim3(16,64), dim3(256), 0, stream>>>(xTh, xT, xx, xxf, idx);
  k_pointwise<<<dim3(256,16), dim3(128), 0, stream>>>(xT, Wc, y1t, y2t, t1t);
  k_s3max<<<dim3(2,256,16), dim3(256), 0, stream>>>(y1t, y2t, idx, Wc, soutT);
  k_tout<<<dim3(4,32,16), dim3(256), 0, stream>>>(t1t, Wc, soutT);
  k_final<<<dim3(64,8,16), dim3(32,8), 0, stream>>>(soutT, d_in[0], flag, d_out);
}

// Round 8
// 1049.368 us; speedup vs baseline: 2.9942x; 1.0755x over previous
//
#include <hip/hip_runtime.h>
#include <hip/hip_bf16.h>
#include <stdint.h>

#define BB 16
#define CC 256
#define NN 2048
#define KK 10
#define WW 128
#define DELTA 0.05f

typedef unsigned short ushort_t;
typedef __attribute__((ext_vector_type(8))) _Float16 half8;
typedef __attribute__((ext_vector_type(8))) short short8;
typedef __attribute__((ext_vector_type(4))) float f32x4;

// converted-weight table offsets (fp32 elements)
#define TW1_O 0
#define TB1_O 32768
#define TW2_O 32896
#define TB2_O 34432
#define TW3_O 34560
#define TB3_O 67328
#define SW1_O 67584
#define SB1_O 133120
#define SW2_O 133248
#define SB2_O 133760
#define SW3_O 133888
#define SB3_O 166656

__device__ __forceinline__ float bflo(unsigned p){ union{unsigned u; float f;} v; v.u = p << 16; return v.f; }
__device__ __forceinline__ float bfhi(unsigned p){ union{unsigned u; float f;} v; v.u = p & 0xffff0000u; return v.f; }
__device__ __forceinline__ float bfs(ushort_t u){ union{unsigned u; float f;} v; v.u = ((unsigned)u) << 16; return v.f; }
__device__ __forceinline__ ushort_t f2bf16(float f){
  __hip_bfloat16 h = __float2bfloat16(f);
  return *reinterpret_cast<ushort_t*>(&h);
}
__device__ __forceinline__ uint2 f4_to_bf4(float4 v){
  uint2 r;
  r.x = (unsigned)f2bf16(v.x) | ((unsigned)f2bf16(v.y) << 16);
  r.y = (unsigned)f2bf16(v.z) | ((unsigned)f2bf16(v.w) << 16);
  return r;
}
__device__ __forceinline__ float max4(f32x4 v){ return fmaxf(fmaxf(v[0],v[1]), fmaxf(v[2],v[3])); }

// wave-parallel input-dtype probe: fp32 data read as bf16 pairs -> garbage exponents.
__device__ __forceinline__ int detect_isf(const void* xraw, int lane){
  unsigned u = ((const unsigned*)xraw)[lane];
  float a = fabsf(bflo(u)), c = fabsf(bfhi(u));
  if(!(a < 1e30f)) a = 1e30f;
  if(!(c < 1e30f)) c = 1e30f;
  float m = fmaxf(a, c);
  #pragma unroll
  for(int off = 32; off > 0; off >>= 1) m = fmaxf(m, __shfl_xor(m, off));
  return m > 1e3f;   // 1 => inputs are fp32
}

// ---------------- D1: convert all weights/biases to fp32 table ----------------
__global__ void k_convw(const void* xraw,
                        const void* p0, const void* p1, const void* p2, const void* p3,
                        const void* p4, const void* p5, const void* p6, const void* p7,
                        const void* p8, const void* p9, const void* p10, const void* p11,
                        float* __restrict__ dst){
  const int counts[12] = {32768,128,1536,128,32768,256,65536,128,512,128,32768,256};
  const int offs[12]   = {TW1_O,TB1_O,TW2_O,TB2_O,TW3_O,TB3_O,SW1_O,SB1_O,SW2_O,SB2_O,SW3_O,SB3_O};
  int a = blockIdx.y;
  const void* src;
  switch(a){
    case 0: src=p0; break; case 1: src=p1; break; case 2: src=p2; break;
    case 3: src=p3; break; case 4: src=p4; break; case 5: src=p5; break;
    case 6: src=p6; break; case 7: src=p7; break; case 8: src=p8; break;
    case 9: src=p9; break; case 10: src=p10; break; default: src=p11; break;
  }
  int isf = detect_isf(xraw, threadIdx.x & 63);
  int cnt = counts[a], off = offs[a];
  for(int i = blockIdx.x*256 + threadIdx.x; i < cnt; i += gridDim.x*256){
    float v = isf ? ((const float*)src)[i] : bfs(((const ushort_t*)src)[i]);
    dst[off + i] = v;
  }
}

// ---------------- D2: canonicalize x -> xT fp32 (B,N,C) + fp16 copy ----------------
__global__ void k_convx(const void* __restrict__ xraw,
                        float* __restrict__ xT, ushort_t* __restrict__ xTh){
  __shared__ float tile[32][33];
  int tx = threadIdx.x, ty = threadIdx.y;
  int isf = detect_isf(xraw, (ty*32 + tx) & 63);
  int b = blockIdx.z;
  int n0 = blockIdx.x * 32;
  int c0 = blockIdx.y * 32;
  #pragma unroll
  for(int r = 0; r < 4; r++){
    int c = c0 + ty + r*8;
    size_t off = ((size_t)b*CC + c)*NN + n0 + tx;
    float v = isf ? ((const float*)xraw)[off] : bfs(((const ushort_t*)xraw)[off]);
    tile[ty + r*8][tx] = v;
  }
  __syncthreads();
  #pragma unroll
  for(int r = 0; r < 4; r++){
    int n = n0 + ty + r*8;
    size_t off = ((size_t)b*NN + n)*CC + c0 + tx;
    float v = tile[tx][ty + r*8];
    xT[off] = v;
    _Float16 h = (_Float16)v;
    xTh[off] = *reinterpret_cast<ushort_t*>(&h);
  }
}

// ---------------- K1: row norms (fp64 + fp32 copy) ----------------
__global__ void k_norms(const float* __restrict__ xT, double* __restrict__ xx,
                        float* __restrict__ xxf){
  int row = blockIdx.x*4 + (threadIdx.x >> 6);
  int lane = threadIdx.x & 63;
  float4 q = *(const float4*)(xT + (size_t)row*CC + lane*4);
  double s = (double)q.x*q.x + (double)q.y*q.y + (double)q.z*q.z + (double)q.w*q.w;
  #pragma unroll
  for(int off = 32; off > 0; off >>= 1) s += __shfl_down(s, off);
  if(lane == 0){ xx[row] = s; xxf[row] = (float)s; }
}

// ---------------- K2a: kNN screen — fp16 MFMA, j-split x2, 5 blocks/CU ----------------
// grid (B, N/32, 2); block 256 (4 waves). i-tile 32 rows; j-half 1024 in 16 chunks of 64.
// Emits per (row, half) the screen top-11 (val,idx).
__global__ __launch_bounds__(256, 5) void k_knn(
    const ushort_t* __restrict__ xTh, const float* __restrict__ xxf,
    float* __restrict__ knnV, int* __restrict__ knnI){
  __shared__ char smem[26368];
  ushort_t* xjh    = (ushort_t*)smem;          // [64][136] fp16 (17408 B)
  float*    keybuf = (float*)(smem + 17408);   // [32][68]       ( 8704 B)
  float*    xxs    = (float*)(smem + 26112);   // [64]           (  256 B)
  float*    mval   = (float*)smem;             // overlay [32][88] (11264 B)
  int*      midx   = (int*)(smem + 11264);     // overlay [32][88] (11264 B)

  const int t    = threadIdx.x;
  const int lane = t & 63;
  const int w    = t >> 6;
  const int b    = blockIdx.x;
  const int i0   = blockIdx.y * 32;
  const int z    = blockIdx.z;
  const size_t xb = (size_t)b * NN;
  const int l15  = lane & 15;
  const int q    = lane >> 4;
  const int jbase = z * 1024;

  // preload A fragments (Xi rows i0..i0+31), fp16, all K=256: 64 VGPRs
  half8 afrag[2][8];
  #pragma unroll
  for(int m = 0; m < 2; m++){
    const ushort_t* pa = xTh + (xb + i0 + 16*m + l15)*CC + q*8;
    #pragma unroll
    for(int ks = 0; ks < 8; ks++)
      afrag[m][ks] = *(const half8*)(pa + ks*32);
  }

  float lv[11]; int li[11];
  #pragma unroll
  for(int k2 = 0; k2 < 11; k2++){ lv[k2] = -3e38f; li[k2] = -1; }

  const int srow = t >> 3;   // selection row 0..31
  const int ssub = t & 7;
  const int grow = t >> 2;   // staging row 0..63
  const int gqtr = t & 3;

  for(int jc = 0; jc < 16; jc++){
    const int j0 = jbase + jc * 64;
    f32x4 acc[2];
    acc[0] = (f32x4){0.f,0.f,0.f,0.f};
    acc[1] = (f32x4){0.f,0.f,0.f,0.f};

    #pragma unroll
    for(int cc = 0; cc < 2; cc++){
      __syncthreads();
      if(cc == 0 && t < 64) xxs[t] = xxf[xb + j0 + t];
      { // stage 64 j-rows x 128 c fp16
        const ushort_t* g = xTh + (xb + j0 + grow)*CC + cc*128 + gqtr*32;
        ushort_t* d = xjh + grow*136 + gqtr*32;
        #pragma unroll
        for(int u = 0; u < 4; u++)
          *(uint4*)(d + u*8) = *(const uint4*)(g + u*8);
      }
      __syncthreads();
      #pragma unroll
      for(int k2 = 0; k2 < 4; k2++){
        const int jr = w*16 + l15;
        half8 bfrag = *(const half8*)(xjh + jr*136 + k2*32 + q*8);
        #pragma unroll
        for(int m = 0; m < 2; m++)
          acc[m] = __builtin_amdgcn_mfma_f32_16x16x32_f16(afrag[m][cc*4+k2], bfrag, acc[m], 0, 0, 0);
      }
    }
    // keys: key = 2*dot - ||xj||^2 ; C/D layout: col=lane&15, row=(lane>>4)*4+reg
    {
      int col = w*16 + l15;
      float xv = xxs[col];
      #pragma unroll
      for(int m = 0; m < 2; m++){
        int rbase = 16*m + q*4;
        #pragma unroll
        for(int r = 0; r < 4; r++)
          keybuf[(rbase + r)*68 + col] = 2.0f*acc[m][r] - xv;
      }
    }
    __syncthreads();
    // selection scan: each thread 8 keys of its row, private top-11
    {
      const float* kp = keybuf + srow*68 + ssub*8;
      #pragma unroll
      for(int e4 = 0; e4 < 2; e4++){
        float4 kv = *(const float4*)(kp + e4*4);
        float ks4[4] = {kv.x, kv.y, kv.z, kv.w};
        #pragma unroll
        for(int e = 0; e < 4; e++){
          float key = ks4[e];
          if(key > lv[10]){
            float cv = key; int ci = j0 + ssub*8 + e4*4 + e;
            #pragma unroll
            for(int k2 = 0; k2 < 11; k2++){
              if(cv > lv[k2]){ float tv = lv[k2]; int ti = li[k2]; lv[k2] = cv; li[k2] = ci; cv = tv; ci = ti; }
            }
          }
        }
      }
    }
  }

  __syncthreads();
  // dump per-thread top-11 (overlays staging region)
  #pragma unroll
  for(int k2 = 0; k2 < 11; k2++){
    mval[srow*88 + ssub*11 + k2] = lv[k2];
    midx[srow*88 + ssub*11 + k2] = li[k2];
  }
  __syncthreads();
  // row leaders: screen top-11 of merged 88 -> global half-result
  if(t < 32){
    float l11[11]; int i11[11];
    #pragma unroll
    for(int k2 = 0; k2 < 11; k2++){ l11[k2] = -3e38f; i11[k2] = -1; }
    for(int e = 0; e < 88; e++){
      float v = mval[t*88 + e];
      if(v > l11[10]){
        float cv = v; int ci = midx[t*88 + e];
        #pragma unroll
        for(int k2 = 0; k2 < 11; k2++){
          if(cv > l11[k2]){ float tv = l11[k2]; int ti = i11[k2]; l11[k2] = cv; i11[k2] = ci; cv = tv; ci = ti; }
        }
      }
    }
    size_t obase = ((xb + i0 + t)*2 + z)*11;
    #pragma unroll
    for(int k2 = 0; k2 < 11; k2++){
      knnV[obase + k2] = l11[k2];
      knnI[obase + k2] = i11[k2];
    }
  }
}

// ---------------- K2b: merge halves + ambiguity fp64 recheck ----------------
// grid (B, N/32); block 256; 32 rows/block, 22 candidates/row.
__global__ __launch_bounds__(256) void k_knnmerge(
    const float* __restrict__ knnV, const int* __restrict__ knnI,
    const float* __restrict__ xT, const double* __restrict__ xx,
    int* __restrict__ idxout){
  __shared__ float  mv[32][22];
  __shared__ int    mi[32][22];
  __shared__ double dk[32][22];
  __shared__ int    ambs[32];
  int b  = blockIdx.x;
  int i0 = blockIdx.y * 32;
  const size_t xb = (size_t)b * NN;
  int t = threadIdx.x;

  for(int e = t; e < 704; e += 256){
    int r = e / 22, k = e - r*22;
    int z = (k >= 11), kk = k - z*11;
    size_t src = ((xb + i0 + r)*2 + z)*11 + kk;
    mv[r][k] = knnV[src];
    mi[r][k] = knnI[src];
  }
  __syncthreads();
  float l11[11]; int i11[11];
  if(t < 32){
    #pragma unroll
    for(int k2 = 0; k2 < 11; k2++){ l11[k2] = -3e38f; i11[k2] = -1; }
    for(int e = 0; e < 22; e++){
      float v = mv[t][e];
      if(v > l11[10]){
        float cv = v; int ci = mi[t][e];
        #pragma unroll
        for(int k2 = 0; k2 < 11; k2++){
          if(cv > l11[k2]){ float tv = l11[k2]; int ti = i11[k2]; l11[k2] = cv; i11[k2] = ci; cv = tv; ci = ti; }
        }
      }
    }
    int amb = (l11[9] - l11[10]) <= (2.0f*DELTA);
    ambs[t] = amb;
    if(!amb){
      size_t obase = ((size_t)b*NN + i0 + t)*KK;
      #pragma unroll
      for(int k2 = 0; k2 < 10; k2++) idxout[obase + k2] = i11[k2];
    }
  }
  __syncthreads();
  // exact fp64 keys for all 22 candidates of ambiguous rows (8 threads/row)
  int srow = t >> 3, ssub = t & 7;
  if(ambs[srow]){
    const float* xip = xT + (xb + i0 + srow)*CC;
    for(int e = ssub; e < 22; e += 8){
      int jg = mi[srow][e];
      const float* xjp = xT + (xb + jg)*CC;
      double s = 0.0;
      for(int c = 0; c < CC; c += 4){
        float4 a4 = *(const float4*)(xip + c);
        float4 b4 = *(const float4*)(xjp + c);
        s += (double)a4.x*b4.x + (double)a4.y*b4.y + (double)a4.z*b4.z + (double)a4.w*b4.w;
      }
      dk[srow][e] = 2.0*s - xx[xb + jg];
    }
  }
  __syncthreads();
  if(t < 32 && ambs[t]){
    double bl[10]; int bi[10];
    #pragma unroll
    for(int k2 = 0; k2 < 10; k2++){ bl[k2] = -1e300; bi[k2] = 0x7fffffff; }
    for(int e = 0; e < 22; e++){
      double v = dk[t][e]; int j2 = mi[t][e];
      if(v > bl[9] || (v == bl[9] && j2 < bi[9])){
        double cv = v; int ci = j2;
        #pragma unroll
        for(int k2 = 0; k2 < 10; k2++){
          if(cv > bl[k2] || (cv == bl[k2] && ci < bi[k2])){
            double tv = bl[k2]; int ti = bi[k2]; bl[k2] = cv; bi[k2] = ci; cv = tv; ci = ti;
          }
        }
      }
    }
    size_t obase = ((size_t)b*NN + i0 + t)*KK;
    #pragma unroll
    for(int k2 = 0; k2 < 10; k2++) idxout[obase + k2] = bi[k2];
  }
}

// ---------------- K3: pointwise convs: y1, y2(+sb1), t1=relu(tw1@x+tb1) ----------------
__global__ __launch_bounds__(128) void k_pointwise(
    const float* __restrict__ xT, const float* __restrict__ Wc,
    float* __restrict__ y1t, float* __restrict__ y2t, float* __restrict__ t1t){
  int b  = blockIdx.y;
  int n0 = blockIdx.x * 16;
  int o  = threadIdx.x;
  const float* w1 = Wc + SW1_O + o*512;
  const float* w2 = w1 + 256;
  const float* w3 = Wc + TW1_O + o*256;
  const float* xr = xT + ((size_t)b*NN + n0)*CC;
  float a1[16], a2[16], a3[16];
  #pragma unroll
  for(int j = 0; j < 16; j++){ a1[j]=0.f; a2[j]=0.f; a3[j]=0.f; }
  for(int c = 0; c < 256; c += 4){
    float4 f1 = *(const float4*)(w1 + c);
    float4 f2 = *(const float4*)(w2 + c);
    float4 f3 = *(const float4*)(w3 + c);
    #pragma unroll
    for(int j = 0; j < 16; j++){
      float4 fx = *(const float4*)(xr + (size_t)j*CC + c);
      a1[j] += f1.x*fx.x + f1.y*fx.y + f1.z*fx.z + f1.w*fx.w;
      a2[j] += f2.x*fx.x + f2.y*fx.y + f2.z*fx.z + f2.w*fx.w;
      a3[j] += f3.x*fx.x + f3.y*fx.y + f3.z*fx.z + f3.w*fx.w;
    }
  }
  float b1 = Wc[SB1_O + o];
  float bt = Wc[TB1_O + o];
  #pragma unroll
  for(int j = 0; j < 16; j++){
    size_t r = ((size_t)b*NN + n0 + j)*WW + o;
    y1t[r] = a1[j];
    y2t[r] = a2[j] + b1;
    t1t[r] = fmaxf(a3[j] + bt, 0.f);
  }
}

// ---------------- K4: graph tail — MFMA GEMM + register max-over-k ----------------
__global__ __launch_bounds__(256, 3) void k_s3max2(
    const float* __restrict__ y1t, const float* __restrict__ y2t,
    const int* __restrict__ idx, const float* __restrict__ Wc,
    float* __restrict__ soutT){
  __shared__ ushort_t w3s[64][136];
  __shared__ ushort_t Us[80][136];
  __shared__ float y2s[8][128];
  __shared__ int idxs[80];
  int b  = blockIdx.z;
  int n0 = blockIdx.y * 8;
  int ch = blockIdx.x;
  int t  = threadIdx.x;
  const int lane = t & 63, w = t >> 6, l15 = lane & 15, q = lane >> 4;

  if(t < 80) idxs[t] = idx[((size_t)b*NN + n0 + t/10)*KK + (t%10)];
  {
    int r = t >> 5, g = t & 31;
    *(float4*)&y2s[r][g*4] = *(const float4*)(y2t + ((size_t)b*NN + n0 + r)*WW + g*4);
  }
  const int g2 = t & 31;
  float4 w2r[4];
  #pragma unroll
  for(int e = 0; e < 4; e++) w2r[e] = *(const float4*)(Wc + SW2_O + (g2*4+e)*4);
  const float4 b2v = *(const float4*)(Wc + SB2_O + g2*4);
  __syncthreads();

  {
    int pr = t >> 5;
    #pragma unroll 2
    for(int it = 0; it < 10; it++){
      int p = it*8 + pr;
      int np = p / 10;
      int j = idxs[p];
      float4 yv = *(const float4*)(y1t + ((size_t)b*NN + j)*WW + g2*4);
      float4 y2v = *(const float4*)&y2s[np][g2*4];
      float v0 = fmaxf(yv.x + y2v.x, 0.f);
      float v1 = fmaxf(yv.y + y2v.y, 0.f);
      float v2 = fmaxf(yv.z + y2v.z, 0.f);
      float v3 = fmaxf(yv.w + y2v.w, 0.f);
      float4 u;
      u.x = fmaxf(b2v.x + w2r[0].x*v0 + w2r[0].y*v1 + w2r[0].z*v2 + w2r[0].w*v3, 0.f);
      u.y = fmaxf(b2v.y + w2r[1].x*v0 + w2r[1].y*v1 + w2r[1].z*v2 + w2r[1].w*v3, 0.f);
      u.z = fmaxf(b2v.z + w2r[2].x*v0 + w2r[2].y*v1 + w2r[2].z*v2 + w2r[2].w*v3, 0.f);
      u.w = fmaxf(b2v.w + w2r[3].x*v0 + w2r[3].y*v1 + w2r[3].z*v2 + w2r[3].w*v3, 0.f);
      *(uint2*)&Us[p][g2*4] = f4_to_bf4(u);
    }
  }

  #pragma unroll
  for(int half = 0; half < 2; half++){
    if(half) __syncthreads();
    {
      int row = t >> 2, qtr = t & 3;
      const float* src = Wc + SW3_O + ((size_t)(ch*128 + half*64 + row))*WW + qtr*32;
      #pragma unroll
      for(int u = 0; u < 8; u++){
        float4 v = *(const float4*)(src + u*4);
        *(uint2*)&w3s[row][qtr*32 + u*4] = f4_to_bf4(v);
      }
    }
    __syncthreads();
    f32x4 a5[5];
    #pragma unroll
    for(int mt = 0; mt < 5; mt++) a5[mt] = (f32x4){0.f,0.f,0.f,0.f};
    #pragma unroll
    for(int k = 0; k < 4; k++){
      short8 bfrag = *(const short8*)(&w3s[w*16 + l15][k*32 + q*8]);
      #pragma unroll
      for(int mt = 0; mt < 5; mt++){
        short8 af = *(const short8*)(&Us[mt*16 + l15][k*32 + q*8]);
        a5[mt] = __builtin_amdgcn_mfma_f32_16x16x32_bf16(af, bfrag, a5[mt], 0, 0, 0);
      }
    }
    float gm[8];
    #pragma unroll
    for(int g = 0; g < 8; g++) gm[g] = -3e38f;
    if(q == 0){
      gm[0]=max4(a5[0]); gm[1]=max4(a5[1]); gm[3]=max4(a5[2]);
      gm[4]=fmaxf(a5[3][0],a5[3][1]); gm[5]=fmaxf(a5[3][2],a5[3][3]); gm[6]=max4(a5[4]);
    } else if(q == 1){
      gm[0]=max4(a5[0]); gm[2]=max4(a5[1]); gm[3]=max4(a5[2]); gm[5]=max4(a5[3]);
      gm[6]=fmaxf(a5[4][0],a5[4][1]); gm[7]=fmaxf(a5[4][2],a5[4][3]);
    } else if(q == 2){
      gm[0]=fmaxf(a5[0][0],a5[0][1]); gm[1]=fmaxf(a5[0][2],a5[0][3]);
      gm[2]=max4(a5[1]); gm[4]=max4(a5[2]); gm[5]=max4(a5[3]); gm[7]=max4(a5[4]);
    } else {
      gm[1]=max4(a5[0]); gm[2]=fmaxf(a5[1][0],a5[1][1]); gm[3]=fmaxf(a5[1][2],a5[1][3]);
      gm[4]=max4(a5[2]); gm[6]=max4(a5[3]); gm[7]=max4(a5[4]);
    }
    #pragma unroll
    for(int g = 0; g < 8; g++){
      float v = gm[g];
      v = fmaxf(v, __shfl_xor(v, 16));
      v = fmaxf(v, __shfl_xor(v, 32));
      gm[g] = v;
    }
    int col = ch*128 + half*64 + w*16 + l15;
    float bias = Wc[SB3_O + col];
    soutT[((size_t)b*NN + n0 + 2*q)*CC + col]     = gm[2*q] + bias;
    soutT[((size_t)b*NN + n0 + 2*q + 1)*CC + col] = gm[2*q+1] + bias;
  }
}

// ---------------- K5: temporal tail: grouped conv3 -> tw3 GEMM; accumulates into soutT ----------------
__global__ __launch_bounds__(256) void k_tout(
    const float* __restrict__ t1t, const float* __restrict__ Wc,
    float* __restrict__ soutT){
  __shared__ float t2s[64][132];
  __shared__ ushort_t w3s[64][132];
  int b  = blockIdx.z;
  int n0 = blockIdx.y * 64;
  int cb = blockIdx.x * 64;
  int t  = threadIdx.x;
  {
    int o = t & 127;
    int rbase = t >> 7;
    float w2v[12];
    #pragma unroll
    for(int z = 0; z < 12; z++) w2v[z] = Wc[TW2_O + o*12 + z];
    float bv = Wc[TB2_O + o];
    int ob = o & ~3;
    for(int e = 0; e < 32; e++){
      int r = rbase + 2*e;
      int n = n0 + r;
      float acc = bv;
      #pragma unroll
      for(int d = 0; d < 3; d++){
        int nn2 = n + d - 1;
        if(nn2 >= 0 && nn2 < NN){
          float4 tv = *(const float4*)(t1t + ((size_t)b*NN + nn2)*WW + ob);
          acc += w2v[0*3+d]*tv.x + w2v[1*3+d]*tv.y + w2v[2*3+d]*tv.z + w2v[3*3+d]*tv.w;
        }
      }
      t2s[r][o] = fmaxf(acc, 0.f);
    }
  }
  #pragma unroll
  for(int e = 0; e < 8; e++){
    int qq = t + 256*e;
    int cl = qq >> 5;
    int c4 = (qq & 31) * 4;
    float4 v = *(const float4*)(Wc + TW3_O + ((size_t)(cb + cl))*WW + c4);
    *(uint2*)&w3s[cl][c4] = f4_to_bf4(v);
  }
  __syncthreads();
  int tr = t >> 4, tc = t & 15;
  float acc[4][4];
  #pragma unroll
  for(int r = 0; r < 4; r++){ acc[r][0]=0.f; acc[r][1]=0.f; acc[r][2]=0.f; acc[r][3]=0.f; }
  for(int w = 0; w < 128; w += 4){
    float4 uv[4];
    #pragma unroll
    for(int r = 0; r < 4; r++) uv[r] = *(const float4*)&t2s[tr+16*r][w];
    float wf[4][4];
    #pragma unroll
    for(int g = 0; g < 4; g++){
      uint2 q = *(const uint2*)&w3s[tc+16*g][w];
      wf[g][0]=bflo(q.x); wf[g][1]=bfhi(q.x); wf[g][2]=bflo(q.y); wf[g][3]=bfhi(q.y);
    }
    #pragma unroll
    for(int r = 0; r < 4; r++){
      #pragma unroll
      for(int g = 0; g < 4; g++)
        acc[r][g] += uv[r].x*wf[g][0] + uv[r].y*wf[g][1] + uv[r].z*wf[g][2] + uv[r].w*wf[g][3];
    }
  }
  #pragma unroll
  for(int g = 0; g < 4; g++){
    float bv = Wc[TB3_O + cb + tc + 16*g];
    #pragma unroll
    for(int r = 0; r < 4; r++){
      size_t off = ((size_t)b*NN + n0 + tr + 16*r)*CC + cb + tc + 16*g;
      soutT[off] = soutT[off] + acc[r][g] + bv;
    }
  }
}

// ---------------- K6: out = relu(comb (transposed) + x), dtype inline-detected ----------------
__global__ void k_final(const float* __restrict__ soutT, const void* __restrict__ xraw,
                        void* __restrict__ outraw){
  __shared__ float tile[32][33];
  int tx = threadIdx.x, ty = threadIdx.y;
  int isf = detect_isf(xraw, (ty*32 + tx) & 63);
  int b = blockIdx.z;
  int n0 = blockIdx.x*32, c0 = blockIdx.y*32;
  #pragma unroll
  for(int r = 0; r < 4; r++){
    int n = n0 + ty + 8*r;
    size_t off = ((size_t)b*NN + n)*CC + c0 + tx;
    tile[ty+8*r][tx] = soutT[off];
  }
  __syncthreads();
  #pragma unroll
  for(int r = 0; r < 4; r++){
    int c = c0 + ty + 8*r;
    size_t off = ((size_t)b*CC + c)*NN + n0 + tx;
    float xv = isf ? ((const float*)xraw)[off] : bfs(((const ushort_t*)xraw)[off]);
    float v = fmaxf(tile[tx][ty+8*r] + xv, 0.f);
    if(isf) ((float*)outraw)[off] = v;
    else    ((ushort_t*)outraw)[off] = f2bf16(v);
  }
}

extern "C" void kernel_launch(void* const* d_in, const int* in_sizes, int n_in,
                              void* d_out, int out_size, void* d_ws, size_t ws_size,
                              hipStream_t stream){
  char* ws = (char*)d_ws;
  // workspace layout (bytes)
  float*    Wc    = (float*)   (ws + 256);          //    667,648
  float*    xT    = (float*)   (ws + 1048576);      // 33,554,432
  double*   xx    = (double*)  (ws + 34603008);     //    262,144
  float*    xxf   = (float*)   (ws + 34865152);     //    131,072
  int*      idx   = (int*)     (ws + 34996224);     //  1,310,720
  float*    y1t   = (float*)   (ws + 36306944);     // 16,777,216
  float*    y2t   = (float*)   (ws + 53084160);     // 16,777,216
  float*    t1t   = (float*)   (ws + 69861376);     // 16,777,216
  float*    soutT = (float*)   (ws + 86638592);     // 33,554,432
  ushort_t* xTh   = (ushort_t*)(ws + 120193024);    // 16,777,216
  float*    knnV  = (float*)   (ws + 136970240);    //  2,883,584
  int*      knnI  = (int*)     (ws + 139853824);    //  2,883,584  (end 142,737,408)

  k_convw<<<dim3(64,12), 256, 0, stream>>>(d_in[0],
                                           d_in[1], d_in[2], d_in[3], d_in[4], d_in[5], d_in[6],
                                           d_in[7], d_in[8], d_in[9], d_in[10], d_in[11], d_in[12],
                                           Wc);
  k_convx<<<dim3(64,8,16), dim3(32,8), 0, stream>>>(d_in[0], xT, xTh);
  k_norms<<<dim3(8192), dim3(256), 0, stream>>>(xT, xx, xxf);
  k_knn<<<dim3(16,64,2), dim3(256), 0, stream>>>(xTh, xxf, knnV, knnI);
  k_knnmerge<<<dim3(16,64), dim3(256), 0, stream>>>(knnV, knnI, xT, xx, idx);
  k_pointwise<<<dim3(128,16), dim3(128), 0, stream>>>(xT, Wc, y1t, y2t, t1t);
  k_s3max2<<<dim3(2,256,16), dim3(256), 0, stream>>>(y1t, y2t, idx, Wc, soutT);
  k_tout<<<dim3(4,32,16), dim3(256), 0, stream>>>(t1t, Wc, soutT);
  k_final<<<dim3(64,8,16), dim3(32,8), 0, stream>>>(soutT, d_in[0], d_out);
}

// Round 9
// 752.826 us; speedup vs baseline: 4.1736x; 1.3939x over previous
//
#include <hip/hip_runtime.h>
#include <hip/hip_bf16.h>
#include <stdint.h>

#define BB 16
#define CC 256
#define NN 2048
#define KK 10
#define WW 128
#define DELTA 0.10f

typedef unsigned short ushort_t;
typedef __attribute__((ext_vector_type(8))) _Float16 half8;
typedef __attribute__((ext_vector_type(8))) short short8;
typedef __attribute__((ext_vector_type(4))) float f32x4;

// converted-weight table offsets (fp32 elements)
#define TW1_O 0
#define TB1_O 32768
#define TW2_O 32896
#define TB2_O 34432
#define TW3_O 34560
#define TB3_O 67328
#define SW1_O 67584
#define SB1_O 133120
#define SW2_O 133248
#define SB2_O 133760
#define SW3_O 133888
#define SB3_O 166656

__device__ __forceinline__ float bflo(unsigned p){ union{unsigned u; float f;} v; v.u = p << 16; return v.f; }
__device__ __forceinline__ float bfhi(unsigned p){ union{unsigned u; float f;} v; v.u = p & 0xffff0000u; return v.f; }
__device__ __forceinline__ float bfs(ushort_t u){ union{unsigned u; float f;} v; v.u = ((unsigned)u) << 16; return v.f; }
__device__ __forceinline__ ushort_t f2bf16(float f){
  __hip_bfloat16 h = __float2bfloat16(f);
  return *reinterpret_cast<ushort_t*>(&h);
}
__device__ __forceinline__ uint2 f4_to_bf4(float4 v){
  uint2 r;
  r.x = (unsigned)f2bf16(v.x) | ((unsigned)f2bf16(v.y) << 16);
  r.y = (unsigned)f2bf16(v.z) | ((unsigned)f2bf16(v.w) << 16);
  return r;
}
__device__ __forceinline__ float max4(f32x4 v){ return fmaxf(fmaxf(v[0],v[1]), fmaxf(v[2],v[3])); }

// packed screen key: sortable-uint(value) high 21 bits | j-index low 11 bits
__device__ __forceinline__ unsigned packkey(float k, int j){
  unsigned u = __float_as_uint(k);
  unsigned s = (u & 0x80000000u) ? ~u : (u | 0x80000000u);
  return (s & 0xFFFFF800u) | (unsigned)j;
}
__device__ __forceinline__ float unpackval(unsigned p){
  unsigned s = p & 0xFFFFF800u;
  unsigned u = (s & 0x80000000u) ? (s & 0x7FFFFFFFu) : ~s;
  return __uint_as_float(u);
}

// wave-parallel input-dtype probe: fp32 data read as bf16 pairs -> garbage exponents.
__device__ __forceinline__ int detect_isf(const void* xraw, int lane){
  unsigned u = ((const unsigned*)xraw)[lane];
  float a = fabsf(bflo(u)), c = fabsf(bfhi(u));
  if(!(a < 1e30f)) a = 1e30f;
  if(!(c < 1e30f)) c = 1e30f;
  float m = fmaxf(a, c);
  #pragma unroll
  for(int off = 32; off > 0; off >>= 1) m = fmaxf(m, __shfl_xor(m, off));
  return m > 1e3f;   // 1 => inputs are fp32
}

// ---------------- D1: convert all weights/biases to fp32 table ----------------
__global__ void k_convw(const void* xraw,
                        const void* p0, const void* p1, const void* p2, const void* p3,
                        const void* p4, const void* p5, const void* p6, const void* p7,
                        const void* p8, const void* p9, const void* p10, const void* p11,
                        float* __restrict__ dst){
  const int counts[12] = {32768,128,1536,128,32768,256,65536,128,512,128,32768,256};
  const int offs[12]   = {TW1_O,TB1_O,TW2_O,TB2_O,TW3_O,TB3_O,SW1_O,SB1_O,SW2_O,SB2_O,SW3_O,SB3_O};
  int a = blockIdx.y;
  const void* src;
  switch(a){
    case 0: src=p0; break; case 1: src=p1; break; case 2: src=p2; break;
    case 3: src=p3; break; case 4: src=p4; break; case 5: src=p5; break;
    case 6: src=p6; break; case 7: src=p7; break; case 8: src=p8; break;
    case 9: src=p9; break; case 10: src=p10; break; default: src=p11; break;
  }
  int isf = detect_isf(xraw, threadIdx.x & 63);
  int cnt = counts[a], off = offs[a];
  for(int i = blockIdx.x*256 + threadIdx.x; i < cnt; i += gridDim.x*256){
    float v = isf ? ((const float*)src)[i] : bfs(((const ushort_t*)src)[i]);
    dst[off + i] = v;
  }
}

// ---------------- D2: canonicalize x -> xT fp32 (B,N,C) + fp16 copy ----------------
__global__ void k_convx(const void* __restrict__ xraw,
                        float* __restrict__ xT, ushort_t* __restrict__ xTh){
  __shared__ float tile[32][33];
  int tx = threadIdx.x, ty = threadIdx.y;
  int isf = detect_isf(xraw, (ty*32 + tx) & 63);
  int b = blockIdx.z;
  int n0 = blockIdx.x * 32;
  int c0 = blockIdx.y * 32;
  #pragma unroll
  for(int r = 0; r < 4; r++){
    int c = c0 + ty + r*8;
    size_t off = ((size_t)b*CC + c)*NN + n0 + tx;
    float v = isf ? ((const float*)xraw)[off] : bfs(((const ushort_t*)xraw)[off]);
    tile[ty + r*8][tx] = v;
  }
  __syncthreads();
  #pragma unroll
  for(int r = 0; r < 4; r++){
    int n = n0 + ty + r*8;
    size_t off = ((size_t)b*NN + n)*CC + c0 + tx;
    float v = tile[tx][ty + r*8];
    xT[off] = v;
    _Float16 h = (_Float16)v;
    xTh[off] = *reinterpret_cast<ushort_t*>(&h);
  }
}

// ---------------- K1: row norms (fp64 + fp32 copy) ----------------
__global__ void k_norms(const float* __restrict__ xT, double* __restrict__ xx,
                        float* __restrict__ xxf){
  int row = blockIdx.x*4 + (threadIdx.x >> 6);
  int lane = threadIdx.x & 63;
  float4 q = *(const float4*)(xT + (size_t)row*CC + lane*4);
  double s = (double)q.x*q.x + (double)q.y*q.y + (double)q.z*q.z + (double)q.w*q.w;
  #pragma unroll
  for(int off = 32; off > 0; off >>= 1) s += __shfl_down(s, off);
  if(lane == 0){ xx[row] = s; xxf[row] = (float)s; }
}

// ---------------- K2a: kNN screen v4 — barrier-free register screen ----------------
// grid (B, N/32); block 256 (4 waves). B-frag (xi, 32 rows) in VGPRs; A-frag (xj)
// streamed from global/L2; per-lane packed top-11 per i-half; no main-loop barriers.
__global__ __launch_bounds__(256, 4) void k_knn(
    const ushort_t* __restrict__ xTh, const float* __restrict__ xxf,
    unsigned* __restrict__ knnP){
  __shared__ float xxs[2048];
  const int t    = threadIdx.x;
  const int lane = t & 63;
  const int w    = t >> 6;
  const int b    = blockIdx.x;
  const int i0   = blockIdx.y * 32;
  const size_t xb = (size_t)b * NN;
  const int l15  = lane & 15;
  const int q    = lane >> 4;

  // stage shifted norms (key = 2*dot - (xx - 256): shrinks |key| for packing)
  for(int e = t; e < 2048; e += 256) xxs[e] = xxf[xb + e] - 256.0f;

  // B-frags: xi rows i0..i0+31 (two 16-row halves), fp16, K=256: 64 VGPRs
  half8 bx0[8], bx1[8];
  {
    const ushort_t* pi0 = xTh + (xb + i0 + l15)*CC + q*8;
    const ushort_t* pi1 = xTh + (xb + i0 + 16 + l15)*CC + q*8;
    #pragma unroll
    for(int ks = 0; ks < 8; ks++){
      bx0[ks] = *(const half8*)(pi0 + ks*32);
      bx1[ks] = *(const half8*)(pi1 + ks*32);
    }
  }

  unsigned lst0[11], lst1[11];
  #pragma unroll
  for(int k2 = 0; k2 < 11; k2++){ lst0[k2] = 0u; lst1[k2] = 0u; }

  __syncthreads();

  for(int jc = 0; jc < 32; jc++){
    const int jrow = jc*64 + w*16 + l15;   // this lane's A-frag row
    const ushort_t* pj = xTh + (xb + jrow)*CC + q*8;
    f32x4 acc0 = (f32x4){0.f,0.f,0.f,0.f};
    f32x4 acc1 = (f32x4){0.f,0.f,0.f,0.f};
    #pragma unroll
    for(int ks = 0; ks < 8; ks++){
      half8 aj = *(const half8*)(pj + ks*32);
      acc0 = __builtin_amdgcn_mfma_f32_16x16x32_f16(aj, bx0[ks], acc0, 0, 0, 0);
      acc1 = __builtin_amdgcn_mfma_f32_16x16x32_f16(aj, bx1[ks], acc1, 0, 0, 0);
    }
    // D rows j = jc*64 + w*16 + 4q + r ; col i = i0 + half*16 + l15
    const int jbase = jc*64 + w*16 + 4*q;
    float4 xxv = *(const float4*)(&xxs[jbase]);
    float xr4[4] = {xxv.x, xxv.y, xxv.z, xxv.w};
    #pragma unroll
    for(int r = 0; r < 4; r++){
      {
        unsigned p = packkey(2.0f*acc0[r] - xr4[r], jbase + r);
        if(p > lst0[10]){
          #pragma unroll
          for(int k2 = 0; k2 < 11; k2++){
            if(p > lst0[k2]){ unsigned tv = lst0[k2]; lst0[k2] = p; p = tv; }
          }
        }
      }
      {
        unsigned p = packkey(2.0f*acc1[r] - xr4[r], jbase + r);
        if(p > lst1[10]){
          #pragma unroll
          for(int k2 = 0; k2 < 11; k2++){
            if(p > lst1[k2]){ unsigned tv = lst1[k2]; lst1[k2] = p; p = tv; }
          }
        }
      }
    }
  }

  // dump: list h -> row (i0 + h*16 + l15), slot (w*4 + q), 11 packed words
  {
    size_t base0 = ((xb + i0 + l15)*16 + (w*4 + q))*11;
    size_t base1 = ((xb + i0 + 16 + l15)*16 + (w*4 + q))*11;
    #pragma unroll
    for(int e = 0; e < 11; e++){
      knnP[base0 + e] = lst0[e];
      knnP[base1 + e] = lst1[e];
    }
  }
}

// ---------------- K2b: merge 176 screen candidates/row + fp64 recheck ----------------
// grid (B, N/32); block 256; 32 rows/block, 8 threads/row.
__global__ __launch_bounds__(256) void k_knnmerge(
    const unsigned* __restrict__ knnP, const float* __restrict__ xT,
    const double* __restrict__ xx, int* __restrict__ idxout){
  __shared__ unsigned Q[32][96];
  __shared__ int    mi[32][12];
  __shared__ double dk[32][12];
  __shared__ int    ambs[32];
  int b  = blockIdx.x;
  int i0 = blockIdx.y * 32;
  const size_t xb = (size_t)b * NN;
  int t = threadIdx.x;
  int r = t >> 3, s8 = t & 7;

  // stage 1: each thread merges 2 slots (22 entries) -> local top-12
  {
    unsigned loc[12];
    #pragma unroll
    for(int k2 = 0; k2 < 12; k2++) loc[k2] = 0u;
    const unsigned* src = knnP + ((xb + i0 + r)*16 + 2*s8)*11;
    #pragma unroll
    for(int e = 0; e < 22; e++){
      unsigned p = src[e];
      if(p > loc[11]){
        #pragma unroll
        for(int k2 = 0; k2 < 12; k2++){
          if(p > loc[k2]){ unsigned tv = loc[k2]; loc[k2] = p; p = tv; }
        }
      }
    }
    #pragma unroll
    for(int k2 = 0; k2 < 12; k2++) Q[r][s8*12 + k2] = loc[k2];
  }
  __syncthreads();
  // stage 2: leader per row merges 96 -> top-12, gap check
  if(t < 32){
    unsigned best[12];
    #pragma unroll
    for(int k2 = 0; k2 < 12; k2++) best[k2] = 0u;
    for(int e = 0; e < 96; e++){
      unsigned p = Q[t][e];
      if(p > best[11]){
        #pragma unroll
        for(int k2 = 0; k2 < 12; k2++){
          if(p > best[k2]){ unsigned tv = best[k2]; best[k2] = p; p = tv; }
        }
      }
    }
    float v9 = unpackval(best[9]), vA = unpackval(best[10]);
    int amb = (v9 - vA) <= (2.0f*DELTA);
    ambs[t] = amb;
    #pragma unroll
    for(int k2 = 0; k2 < 12; k2++) mi[t][k2] = (int)(best[k2] & 0x7FFu);
    if(!amb){
      size_t obase = ((size_t)b*NN + i0 + t)*KK;
      #pragma unroll
      for(int k2 = 0; k2 < 10; k2++) idxout[obase + k2] = mi[t][k2];
    }
  }
  __syncthreads();
  // recheck: exact fp64 keys for 12 candidates of ambiguous rows
  if(ambs[r]){
    const float* xip = xT + (xb + i0 + r)*CC;
    for(int e = s8; e < 12; e += 8){
      int jg = mi[r][e];
      const float* xjp = xT + (xb + jg)*CC;
      double s = 0.0;
      for(int c = 0; c < CC; c += 4){
        float4 a4 = *(const float4*)(xip + c);
        float4 b4 = *(const float4*)(xjp + c);
        s += (double)a4.x*b4.x + (double)a4.y*b4.y + (double)a4.z*b4.z + (double)a4.w*b4.w;
      }
      dk[r][e] = 2.0*s - xx[xb + jg];
    }
  }
  __syncthreads();
  if(t < 32 && ambs[t]){
    double bl[10]; int bi[10];
    #pragma unroll
    for(int k2 = 0; k2 < 10; k2++){ bl[k2] = -1e300; bi[k2] = 0x7fffffff; }
    for(int e = 0; e < 12; e++){
      double v = dk[t][e]; int j2 = mi[t][e];
      if(v > bl[9] || (v == bl[9] && j2 < bi[9])){
        double cv = v; int ci = j2;
        #pragma unroll
        for(int k2 = 0; k2 < 10; k2++){
          if(cv > bl[k2] || (cv == bl[k2] && ci < bi[k2])){
            double tv = bl[k2]; int ti = bi[k2]; bl[k2] = cv; bi[k2] = ci; cv = tv; ci = ti;
          }
        }
      }
    }
    size_t obase = ((size_t)b*NN + i0 + t)*KK;
    #pragma unroll
    for(int k2 = 0; k2 < 10; k2++) idxout[obase + k2] = bi[k2];
  }
}

// ---------------- K3: pointwise convs: y1, y2(+sb1), t1=relu(tw1@x+tb1) ----------------
__global__ __launch_bounds__(128) void k_pointwise(
    const float* __restrict__ xT, const float* __restrict__ Wc,
    float* __restrict__ y1t, float* __restrict__ y2t, float* __restrict__ t1t){
  int b  = blockIdx.y;
  int n0 = blockIdx.x * 16;
  int o  = threadIdx.x;
  const float* w1 = Wc + SW1_O + o*512;
  const float* w2 = w1 + 256;
  const float* w3 = Wc + TW1_O + o*256;
  const float* xr = xT + ((size_t)b*NN + n0)*CC;
  float a1[16], a2[16], a3[16];
  #pragma unroll
  for(int j = 0; j < 16; j++){ a1[j]=0.f; a2[j]=0.f; a3[j]=0.f; }
  for(int c = 0; c < 256; c += 4){
    float4 f1 = *(const float4*)(w1 + c);
    float4 f2 = *(const float4*)(w2 + c);
    float4 f3 = *(const float4*)(w3 + c);
    #pragma unroll
    for(int j = 0; j < 16; j++){
      float4 fx = *(const float4*)(xr + (size_t)j*CC + c);
      a1[j] += f1.x*fx.x + f1.y*fx.y + f1.z*fx.z + f1.w*fx.w;
      a2[j] += f2.x*fx.x + f2.y*fx.y + f2.z*fx.z + f2.w*fx.w;
      a3[j] += f3.x*fx.x + f3.y*fx.y + f3.z*fx.z + f3.w*fx.w;
    }
  }
  float b1 = Wc[SB1_O + o];
  float bt = Wc[TB1_O + o];
  #pragma unroll
  for(int j = 0; j < 16; j++){
    size_t r = ((size_t)b*NN + n0 + j)*WW + o;
    y1t[r] = a1[j];
    y2t[r] = a2[j] + b1;
    t1t[r] = fmaxf(a3[j] + bt, 0.f);
  }
}

// ---------------- K4: graph tail — MFMA GEMM + register max-over-k ----------------
__global__ __launch_bounds__(256, 3) void k_s3max2(
    const float* __restrict__ y1t, const float* __restrict__ y2t,
    const int* __restrict__ idx, const float* __restrict__ Wc,
    float* __restrict__ soutT){
  __shared__ ushort_t w3s[64][136];
  __shared__ ushort_t Us[80][136];
  __shared__ float y2s[8][128];
  __shared__ int idxs[80];
  int b  = blockIdx.z;
  int n0 = blockIdx.y * 8;
  int ch = blockIdx.x;
  int t  = threadIdx.x;
  const int lane = t & 63, w = t >> 6, l15 = lane & 15, q = lane >> 4;

  if(t < 80) idxs[t] = idx[((size_t)b*NN + n0 + t/10)*KK + (t%10)];
  {
    int r = t >> 5, g = t & 31;
    *(float4*)&y2s[r][g*4] = *(const float4*)(y2t + ((size_t)b*NN + n0 + r)*WW + g*4);
  }
  const int g2 = t & 31;
  float4 w2r[4];
  #pragma unroll
  for(int e = 0; e < 4; e++) w2r[e] = *(const float4*)(Wc + SW2_O + (g2*4+e)*4);
  const float4 b2v = *(const float4*)(Wc + SB2_O + g2*4);
  __syncthreads();

  {
    int pr = t >> 5;
    #pragma unroll 2
    for(int it = 0; it < 10; it++){
      int p = it*8 + pr;
      int np = p / 10;
      int j = idxs[p];
      float4 yv = *(const float4*)(y1t + ((size_t)b*NN + j)*WW + g2*4);
      float4 y2v = *(const float4*)&y2s[np][g2*4];
      float v0 = fmaxf(yv.x + y2v.x, 0.f);
      float v1 = fmaxf(yv.y + y2v.y, 0.f);
      float v2 = fmaxf(yv.z + y2v.z, 0.f);
      float v3 = fmaxf(yv.w + y2v.w, 0.f);
      float4 u;
      u.x = fmaxf(b2v.x + w2r[0].x*v0 + w2r[0].y*v1 + w2r[0].z*v2 + w2r[0].w*v3, 0.f);
      u.y = fmaxf(b2v.y + w2r[1].x*v0 + w2r[1].y*v1 + w2r[1].z*v2 + w2r[1].w*v3, 0.f);
      u.z = fmaxf(b2v.z + w2r[2].x*v0 + w2r[2].y*v1 + w2r[2].z*v2 + w2r[2].w*v3, 0.f);
      u.w = fmaxf(b2v.w + w2r[3].x*v0 + w2r[3].y*v1 + w2r[3].z*v2 + w2r[3].w*v3, 0.f);
      *(uint2*)&Us[p][g2*4] = f4_to_bf4(u);
    }
  }

  #pragma unroll
  for(int half = 0; half < 2; half++){
    if(half) __syncthreads();
    {
      int row = t >> 2, qtr = t & 3;
      const float* src = Wc + SW3_O + ((size_t)(ch*128 + half*64 + row))*WW + qtr*32;
      #pragma unroll
      for(int u = 0; u < 8; u++){
        float4 v = *(const float4*)(src + u*4);
        *(uint2*)&w3s[row][qtr*32 + u*4] = f4_to_bf4(v);
      }
    }
    __syncthreads();
    f32x4 a5[5];
    #pragma unroll
    for(int mt = 0; mt < 5; mt++) a5[mt] = (f32x4){0.f,0.f,0.f,0.f};
    #pragma unroll
    for(int k = 0; k < 4; k++){
      short8 bfrag = *(const short8*)(&w3s[w*16 + l15][k*32 + q*8]);
      #pragma unroll
      for(int mt = 0; mt < 5; mt++){
        short8 af = *(const short8*)(&Us[mt*16 + l15][k*32 + q*8]);
        a5[mt] = __builtin_amdgcn_mfma_f32_16x16x32_bf16(af, bfrag, a5[mt], 0, 0, 0);
      }
    }
    float gm[8];
    #pragma unroll
    for(int g = 0; g < 8; g++) gm[g] = -3e38f;
    if(q == 0){
      gm[0]=max4(a5[0]); gm[1]=max4(a5[1]); gm[3]=max4(a5[2]);
      gm[4]=fmaxf(a5[3][0],a5[3][1]); gm[5]=fmaxf(a5[3][2],a5[3][3]); gm[6]=max4(a5[4]);
    } else if(q == 1){
      gm[0]=max4(a5[0]); gm[2]=max4(a5[1]); gm[3]=max4(a5[2]); gm[5]=max4(a5[3]);
      gm[6]=fmaxf(a5[4][0],a5[4][1]); gm[7]=fmaxf(a5[4][2],a5[4][3]);
    } else if(q == 2){
      gm[0]=fmaxf(a5[0][0],a5[0][1]); gm[1]=fmaxf(a5[0][2],a5[0][3]);
      gm[2]=max4(a5[1]); gm[4]=max4(a5[2]); gm[5]=max4(a5[3]); gm[7]=max4(a5[4]);
    } else {
      gm[1]=max4(a5[0]); gm[2]=fmaxf(a5[1][0],a5[1][1]); gm[3]=fmaxf(a5[1][2],a5[1][3]);
      gm[4]=max4(a5[2]); gm[6]=max4(a5[3]); gm[7]=max4(a5[4]);
    }
    #pragma unroll
    for(int g = 0; g < 8; g++){
      float v = gm[g];
      v = fmaxf(v, __shfl_xor(v, 16));
      v = fmaxf(v, __shfl_xor(v, 32));
      gm[g] = v;
    }
    int col = ch*128 + half*64 + w*16 + l15;
    float bias = Wc[SB3_O + col];
    soutT[((size_t)b*NN + n0 + 2*q)*CC + col]     = gm[2*q] + bias;
    soutT[((size_t)b*NN + n0 + 2*q + 1)*CC + col] = gm[2*q+1] + bias;
  }
}

// ---------------- K5: temporal tail: grouped conv3 -> tw3 GEMM; accumulates into soutT ----------------
__global__ __launch_bounds__(256) void k_tout(
    const float* __restrict__ t1t, const float* __restrict__ Wc,
    float* __restrict__ soutT){
  __shared__ float t2s[64][132];
  __shared__ ushort_t w3s[64][132];
  int b  = blockIdx.z;
  int n0 = blockIdx.y * 64;
  int cb = blockIdx.x * 64;
  int t  = threadIdx.x;
  {
    int o = t & 127;
    int rbase = t >> 7;
    float w2v[12];
    #pragma unroll
    for(int z = 0; z < 12; z++) w2v[z] = Wc[TW2_O + o*12 + z];
    float bv = Wc[TB2_O + o];
    int ob = o & ~3;
    for(int e = 0; e < 32; e++){
      int r = rbase + 2*e;
      int n = n0 + r;
      float acc = bv;
      #pragma unroll
      for(int d = 0; d < 3; d++){
        int nn2 = n + d - 1;
        if(nn2 >= 0 && nn2 < NN){
          float4 tv = *(const float4*)(t1t + ((size_t)b*NN + nn2)*WW + ob);
          acc += w2v[0*3+d]*tv.x + w2v[1*3+d]*tv.y + w2v[2*3+d]*tv.z + w2v[3*3+d]*tv.w;
        }
      }
      t2s[r][o] = fmaxf(acc, 0.f);
    }
  }
  #pragma unroll
  for(int e = 0; e < 8; e++){
    int qq = t + 256*e;
    int cl = qq >> 5;
    int c4 = (qq & 31) * 4;
    float4 v = *(const float4*)(Wc + TW3_O + ((size_t)(cb + cl))*WW + c4);
    *(uint2*)&w3s[cl][c4] = f4_to_bf4(v);
  }
  __syncthreads();
  int tr = t >> 4, tc = t & 15;
  float acc[4][4];
  #pragma unroll
  for(int r = 0; r < 4; r++){ acc[r][0]=0.f; acc[r][1]=0.f; acc[r][2]=0.f; acc[r][3]=0.f; }
  for(int w = 0; w < 128; w += 4){
    float4 uv[4];
    #pragma unroll
    for(int r = 0; r < 4; r++) uv[r] = *(const float4*)&t2s[tr+16*r][w];
    float wf[4][4];
    #pragma unroll
    for(int g = 0; g < 4; g++){
      uint2 q = *(const uint2*)&w3s[tc+16*g][w];
      wf[g][0]=bflo(q.x); wf[g][1]=bfhi(q.x); wf[g][2]=bflo(q.y); wf[g][3]=bfhi(q.y);
    }
    #pragma unroll
    for(int r = 0; r < 4; r++){
      #pragma unroll
      for(int g = 0; g < 4; g++)
        acc[r][g] += uv[r].x*wf[g][0] + uv[r].y*wf[g][1] + uv[r].z*wf[g][2] + uv[r].w*wf[g][3];
    }
  }
  #pragma unroll
  for(int g = 0; g < 4; g++){
    float bv = Wc[TB3_O + cb + tc + 16*g];
    #pragma unroll
    for(int r = 0; r < 4; r++){
      size_t off = ((size_t)b*NN + n0 + tr + 16*r)*CC + cb + tc + 16*g;
      soutT[off] = soutT[off] + acc[r][g] + bv;
    }
  }
}

// ---------------- K6: out = relu(comb (transposed) + x), dtype inline-detected ----------------
__global__ void k_final(const float* __restrict__ soutT, const void* __restrict__ xraw,
                        void* __restrict__ outraw){
  __shared__ float tile[32][33];
  int tx = threadIdx.x, ty = threadIdx.y;
  int isf = detect_isf(xraw, (ty*32 + tx) & 63);
  int b = blockIdx.z;
  int n0 = blockIdx.x*32, c0 = blockIdx.y*32;
  #pragma unroll
  for(int r = 0; r < 4; r++){
    int n = n0 + ty + 8*r;
    size_t off = ((size_t)b*NN + n)*CC + c0 + tx;
    tile[ty+8*r][tx] = soutT[off];
  }
  __syncthreads();
  #pragma unroll
  for(int r = 0; r < 4; r++){
    int c = c0 + ty + 8*r;
    size_t off = ((size_t)b*CC + c)*NN + n0 + tx;
    float xv = isf ? ((const float*)xraw)[off] : bfs(((const ushort_t*)xraw)[off]);
    float v = fmaxf(tile[tx][ty+8*r] + xv, 0.f);
    if(isf) ((float*)outraw)[off] = v;
    else    ((ushort_t*)outraw)[off] = f2bf16(v);
  }
}

extern "C" void kernel_launch(void* const* d_in, const int* in_sizes, int n_in,
                              void* d_out, int out_size, void* d_ws, size_t ws_size,
                              hipStream_t stream){
  char* ws = (char*)d_ws;
  // workspace layout (bytes)
  float*    Wc    = (float*)   (ws + 256);          //    667,648
  float*    xT    = (float*)   (ws + 1048576);      // 33,554,432
  double*   xx    = (double*)  (ws + 34603008);     //    262,144
  float*    xxf   = (float*)   (ws + 34865152);     //    131,072
  int*      idx   = (int*)     (ws + 34996224);     //  1,310,720
  float*    y1t   = (float*)   (ws + 36306944);     // 16,777,216
  float*    y2t   = (float*)   (ws + 53084160);     // 16,777,216
  float*    t1t   = (float*)   (ws + 69861376);     // 16,777,216
  float*    soutT = (float*)   (ws + 86638592);     // 33,554,432
  ushort_t* xTh   = (ushort_t*)(ws + 120193024);    // 16,777,216
  unsigned* knnP  = (unsigned*)(ws + 136970240);    // 23,068,672  (end 160,038,912)

  k_convw<<<dim3(64,12), 256, 0, stream>>>(d_in[0],
                                           d_in[1], d_in[2], d_in[3], d_in[4], d_in[5], d_in[6],
                                           d_in[7], d_in[8], d_in[9], d_in[10], d_in[11], d_in[12],
                                           Wc);
  k_convx<<<dim3(64,8,16), dim3(32,8), 0, stream>>>(d_in[0], xT, xTh);
  k_norms<<<dim3(8192), dim3(256), 0, stream>>>(xT, xx, xxf);
  k_knn<<<dim3(16,64), dim3(256), 0, stream>>>(xTh, xxf, knnP);
  k_knnmerge<<<dim3(16,64), dim3(256), 0, stream>>>(knnP, xT, xx, idx);
  k_pointwise<<<dim3(128,16), dim3(128), 0, stream>>>(xT, Wc, y1t, y2t, t1t);
  k_s3max2<<<dim3(2,256,16), dim3(256), 0, stream>>>(y1t, y2t, idx, Wc, soutT);
  k_tout<<<dim3(4,32,16), dim3(256), 0, stream>>>(t1t, Wc, soutT);
  k_final<<<dim3(64,8,16), dim3(32,8), 0, stream>>>(soutT, d_in[0], d_out);
}